// Round 6
// baseline (453.797 us; speedup 1.0000x reference)
//
#include <hip/hip_runtime.h>

// HeteroGNN fused implementation, round 6.
// Algebra: new = relu( S @ W1 + deg.*(x @ W2) + x @ W3 + deg.*bmp + bu )
// Round-6: layer-2 GEMM moves 4x8 -> 8x8 micro-tile (0.75 -> 0.5 LDS B/FLOP;
// LDS-bound 92 TF -> FMA-bound) while staying single-buffered (round-4's
// double-buffer VGPR blowup avoided). BM=128, BK=16, 17KB LDS.

#define H 128
#define NN 50000
#define NL 50000
#define NE 400000
#define NG 64
#define FR 8
#define SNB 49

// ---------------- weight fusion ----------------
__global__ void precompute_w(const float* __restrict__ Wm_nl, const float* __restrict__ bm_nl,
                             const float* __restrict__ Wu_nl,
                             const float* __restrict__ Wm_ln, const float* __restrict__ bm_ln,
                             const float* __restrict__ Wu_ln,
                             float* __restrict__ Wstack, float* __restrict__ bmp) {
    int idx = blockIdx.x * blockDim.x + threadIdx.x;
    const int per = 384 * H + H;
    int c = idx / per, r = idx % per;
    if (c >= 4) return;
    int l = c >> 1, rel = c & 1;
    const float* Wm = (rel ? Wm_ln : Wm_nl) + l * 256 * H;
    const float* Wu = (rel ? Wu_ln : Wu_nl) + l * 256 * H;
    const float* bm = (rel ? bm_ln : bm_nl) + l * H;
    float* Ws = Wstack + c * 384 * H;
    if (r < 384 * H) {
        int t = r / H, j = r % H;
        if (t < 256) {
            float acc = 0.f;
            for (int k = 0; k < H; ++k) acc += Wm[t * H + k] * Wu[k * H + j];
            Ws[t * H + j] = acc;
        } else {
            Ws[t * H + j] = Wu[(t - 128) * H + j];
        }
    } else {
        int j = r - 384 * H;
        float acc = 0.f;
        for (int k = 0; k < H; ++k) acc += bm[k] * Wu[k * H + j];
        bmp[c * H + j] = acc;
    }
}

// ---------------- degree (int) ----------------
__global__ void compute_deg(const int* __restrict__ nl, const int* __restrict__ ln,
                            int* __restrict__ dl, int* __restrict__ dn) {
    int e = blockIdx.x * blockDim.x + threadIdx.x;
    if (e < NE) {
        atomicAdd(&dl[nl[NE + e]], 1);
        atomicAdd(&dn[ln[NE + e]], 1);
    }
}

// ---------------- 3-phase parallel scan ----------------
__global__ void scan1(const int* __restrict__ degL, const int* __restrict__ degN,
                      int* __restrict__ bsum) {
    int arr = blockIdx.x / SNB, blk = blockIdx.x % SNB;
    const int* deg = arr ? degN : degL;
    int tid = threadIdx.x;
    int base = blk * 1024 + tid * 4;
    int s = 0;
#pragma unroll
    for (int i = 0; i < 4; ++i) { int idx = base + i; if (idx < NL) s += deg[idx]; }
    __shared__ int red[256];
    red[tid] = s;
    __syncthreads();
    for (int d = 128; d > 0; d >>= 1) {
        if (tid < d) red[tid] += red[tid + d];
        __syncthreads();
    }
    if (tid == 0) bsum[blockIdx.x] = red[0];
}

__global__ void scan2(const int* __restrict__ bsum, int* __restrict__ bbase) {
    __shared__ int sh[128];
    int tid = threadIdx.x;
    int v0 = (tid < 2 * SNB) ? bsum[tid] : 0;
    sh[tid] = v0;
    __syncthreads();
    int gstart = (tid < SNB) ? 0 : SNB;
    for (int d = 1; d < 64; d <<= 1) {
        int v = (tid >= gstart + d && tid < 2 * SNB) ? sh[tid - d] : 0;
        __syncthreads();
        sh[tid] += v;
        __syncthreads();
    }
    if (tid < 2 * SNB) bbase[tid] = sh[tid] - v0;
}

__global__ void scan3(const int* __restrict__ degL, const int* __restrict__ degN,
                      const int* __restrict__ bbase,
                      int* __restrict__ offL, int* __restrict__ offN,
                      int* __restrict__ curL, int* __restrict__ curN,
                      float* __restrict__ fdegL, float* __restrict__ fdegN) {
    int arr = blockIdx.x / SNB, blk = blockIdx.x % SNB;
    const int* deg = arr ? degN : degL;
    int* off = arr ? offN : offL;
    int* cur = arr ? curN : curL;
    float* fdeg = arr ? fdegN : fdegL;
    int tid = threadIdx.x;
    int base = blk * 1024 + tid * 4;
    int d4[4]; int s = 0;
#pragma unroll
    for (int i = 0; i < 4; ++i) {
        int idx = base + i;
        d4[i] = (idx < NL) ? deg[idx] : 0;
        s += d4[i];
    }
    __shared__ int part[256];
    part[tid] = s;
    __syncthreads();
    for (int d = 1; d < 256; d <<= 1) {
        int v = (tid >= d) ? part[tid - d] : 0;
        __syncthreads();
        part[tid] += v;
        __syncthreads();
    }
    int run = bbase[blockIdx.x] + part[tid] - s;
#pragma unroll
    for (int i = 0; i < 4; ++i) {
        int idx = base + i;
        if (idx < NL) {
            off[idx] = run; cur[idx] = run; fdeg[idx] = (float)d4[i];
            run += d4[i];
            if (idx == NL - 1) off[NL] = run;
        }
    }
}

// ---------------- CSR fill ----------------
__global__ void fill_csr(const int* __restrict__ nl, const int* __restrict__ ln,
                         int* __restrict__ curL, int* __restrict__ curN,
                         int* __restrict__ adjL, int* __restrict__ adjN) {
    int e = blockIdx.x * blockDim.x + threadIdx.x;
    if (e >= NE) return;
    {
        int src = nl[e], dst = nl[NE + e];
        int p = atomicAdd(&curL[dst], 1);
        adjL[p] = src;
    }
    {
        int src = ln[e], dst = ln[NE + e];
        int p = atomicAdd(&curN[dst], 1);
        adjN[p] = src;
    }
}

// ---------------- layer-1 gather (raw 8-col), both relations ----------------
__launch_bounds__(256)
__global__ void gather_sum8_2(const int* __restrict__ offL, const int* __restrict__ adjL,
                              const float* __restrict__ xnode, float* __restrict__ S8l,
                              const int* __restrict__ offN, const int* __restrict__ adjN,
                              const float* __restrict__ xlink, float* __restrict__ S8n) {
    int rel = blockIdx.y;
    const int* off = rel ? offN : offL;
    const int* adj = rel ? adjN : adjL;
    const float* Xr = rel ? xlink : xnode;
    float* S8 = rel ? S8n : S8l;
    int t = blockIdx.x * 256 + threadIdx.x;
    int row = t >> 3, c = t & 7;
    if (row >= NL) return;
    int beg = off[row], end = off[row + 1];
    float acc = 0.f;
    for (int i = beg; i < end; ++i)
        acc += Xr[(size_t)adj[i] * FR + c];
    S8[row * FR + c] = acc;
}

// ---------------- layer-2 gather, both relations, 32-lane float4 rows ----------------
__launch_bounds__(256)
__global__ void gather_sum2(const int* __restrict__ offL, const int* __restrict__ adjL,
                            const float* __restrict__ xnp, float* __restrict__ Sl,
                            const int* __restrict__ offN, const int* __restrict__ adjN,
                            const float* __restrict__ xlp, float* __restrict__ Sn) {
    int rel = blockIdx.y;
    const int* off = rel ? offN : offL;
    const int* adj = rel ? adjN : adjL;
    const float* X = rel ? xlp : xnp;
    float* Sg = rel ? Sn : Sl;
    int row = blockIdx.x * 8 + (threadIdx.x >> 5);
    int lane = threadIdx.x & 31;
    if (row >= NL) return;
    int beg = off[row], end = off[row + 1];
    float ax = 0.f, ay = 0.f, az = 0.f, aw = 0.f;
    float bx = 0.f, by = 0.f, bz = 0.f, bw = 0.f;
    int i = beg;
    for (; i + 1 < end; i += 2) {
        float4 a = *(const float4*)(X + (size_t)adj[i] * H + lane * 4);
        float4 b = *(const float4*)(X + (size_t)adj[i + 1] * H + lane * 4);
        ax += a.x; ay += a.y; az += a.z; aw += a.w;
        bx += b.x; by += b.y; bz += b.z; bw += b.w;
    }
    if (i < end) {
        float4 a = *(const float4*)(X + (size_t)adj[i] * H + lane * 4);
        ax += a.x; ay += a.y; az += a.z; aw += a.w;
    }
    float4 r = make_float4(ax + bx, ay + by, az + bz, aw + bw);
    *(float4*)(Sg + (size_t)row * H + lane * 4) = r;
}

// ---------------- layer-2 fused GEMM, both relations: 8x8 micro, single-buffer ----------------
// Out = relu([S | deg.*X | X] @ Ws + deg.*bmp + bu)
// BM=128 rows, BN=128 cols, BK=16. 256 threads; thread (rowt,colt) owns rows
// {rowt*4+i, 64+rowt*4+i} x cols {colt*4+j, 64+colt*4+j}.
#define GBM 128
#define GBK 16
__launch_bounds__(256)
__global__ void gemm_update4(const float* __restrict__ Sl, const float* __restrict__ xlp,
                             const float* __restrict__ dgl,
                             const float* __restrict__ Sn, const float* __restrict__ xnp,
                             const float* __restrict__ dgn,
                             const float* __restrict__ Wstack, const float* __restrict__ bmpAll,
                             const float* __restrict__ bu_nl, const float* __restrict__ bu_ln,
                             float* __restrict__ outl, float* __restrict__ outn, int M) {
    int rel = blockIdx.y;
    const float* S   = rel ? Sn : Sl;
    const float* X   = rel ? xnp : xlp;
    const float* deg = rel ? dgn : dgl;
    const float* Ws  = Wstack + (size_t)(2 + rel) * 384 * H;
    const float* bmp = bmpAll + (2 + rel) * H;
    const float* bu  = (rel ? bu_ln : bu_nl) + H;   // layer index 1
    float* Out = rel ? outn : outl;

    __shared__ float At[GBK][GBM + 4];   // 16 x 132
    __shared__ float Bt[GBK][H + 8];     // 16 x 136

    int tid = threadIdx.x;
    int rowt = tid >> 4;     // 0..15
    int colt = tid & 15;     // 0..15
    int m0 = blockIdx.x * GBM;

    // staging mapping
    int kg = tid & 3;            // k-chunk (4 floats)
    int rs = tid >> 2;           // 0..63 base row
    int row0 = m0 + rs, row1 = m0 + rs + 64;
    bool v0 = row0 < M, v1 = row1 < M;
    float d0 = v0 ? deg[row0] : 0.f;
    float d1 = v1 ? deg[row1] : 0.f;
    int kkb = tid >> 5;          // 0..7 for B staging
    int c4 = tid & 31;

    float acc[8][8] = {};

    for (int k0 = 0; k0 < 384; k0 += GBK) {
        int piece = k0 >> 7;               // 0:S 1:deg*X 2:X (constant in step)
        int kin = (k0 & 127) + kg * 4;
        const float* Asrc = (piece == 0) ? S : X;
        float4 a0 = v0 ? *(const float4*)(Asrc + (size_t)row0 * H + kin)
                       : make_float4(0.f, 0.f, 0.f, 0.f);
        float4 a1 = v1 ? *(const float4*)(Asrc + (size_t)row1 * H + kin)
                       : make_float4(0.f, 0.f, 0.f, 0.f);
        if (piece == 1) {
            a0.x *= d0; a0.y *= d0; a0.z *= d0; a0.w *= d0;
            a1.x *= d1; a1.y *= d1; a1.z *= d1; a1.w *= d1;
        }
        float4 b0 = *(const float4*)(Ws + (size_t)(k0 + kkb) * H + c4 * 4);
        float4 b1 = *(const float4*)(Ws + (size_t)(k0 + kkb + 8) * H + c4 * 4);

        At[kg * 4 + 0][rs] = a0.x; At[kg * 4 + 1][rs] = a0.y;
        At[kg * 4 + 2][rs] = a0.z; At[kg * 4 + 3][rs] = a0.w;
        At[kg * 4 + 0][rs + 64] = a1.x; At[kg * 4 + 1][rs + 64] = a1.y;
        At[kg * 4 + 2][rs + 64] = a1.z; At[kg * 4 + 3][rs + 64] = a1.w;
        *(float4*)(&Bt[kkb][c4 * 4]) = b0;
        *(float4*)(&Bt[kkb + 8][c4 * 4]) = b1;
        __syncthreads();

#pragma unroll
        for (int kk = 0; kk < GBK; ++kk) {
            float a[8], b[8];
            *(float4*)(a)     = *(const float4*)(&At[kk][rowt * 4]);
            *(float4*)(a + 4) = *(const float4*)(&At[kk][64 + rowt * 4]);
            *(float4*)(b)     = *(const float4*)(&Bt[kk][colt * 4]);
            *(float4*)(b + 4) = *(const float4*)(&Bt[kk][64 + colt * 4]);
#pragma unroll
            for (int i = 0; i < 8; ++i)
#pragma unroll
                for (int j = 0; j < 8; ++j)
                    acc[i][j] += a[i] * b[j];
        }
        __syncthreads();
    }

    int c0 = colt * 4, c1 = 64 + colt * 4;
    float4 bm0 = *(const float4*)(bmp + c0), bm1 = *(const float4*)(bmp + c1);
    float4 bb0 = *(const float4*)(bu + c0),  bb1 = *(const float4*)(bu + c1);
#pragma unroll
    for (int i = 0; i < 8; ++i) {
        int row = m0 + (i < 4 ? rowt * 4 + i : 64 + rowt * 4 + (i - 4));
        if (row < M) {
            float d = deg[row];
            float4 o0, o1;
            o0.x = fmaxf(acc[i][0] + d * bm0.x + bb0.x, 0.f);
            o0.y = fmaxf(acc[i][1] + d * bm0.y + bb0.y, 0.f);
            o0.z = fmaxf(acc[i][2] + d * bm0.z + bb0.z, 0.f);
            o0.w = fmaxf(acc[i][3] + d * bm0.w + bb0.w, 0.f);
            o1.x = fmaxf(acc[i][4] + d * bm1.x + bb1.x, 0.f);
            o1.y = fmaxf(acc[i][5] + d * bm1.y + bb1.y, 0.f);
            o1.z = fmaxf(acc[i][6] + d * bm1.z + bb1.z, 0.f);
            o1.w = fmaxf(acc[i][7] + d * bm1.w + bb1.w, 0.f);
            *(float4*)(Out + (size_t)row * H + c0) = o0;
            *(float4*)(Out + (size_t)row * H + c1) = o1;
        }
    }
}

// ---------------- layer-1 fused GEMM (K=24), both relations ----------------
#define BM 64
__launch_bounds__(256)
__global__ void gemm_update_l1_2(const float* __restrict__ S8l, const float* __restrict__ xlink,
                                 const float* __restrict__ dgl,
                                 const float* __restrict__ S8n, const float* __restrict__ xnode,
                                 const float* __restrict__ dgn,
                                 const float* __restrict__ Wstack, const float* __restrict__ bmpAll,
                                 const float* __restrict__ bu_nl, const float* __restrict__ bu_ln,
                                 float* __restrict__ outl, float* __restrict__ outn, int M) {
    int rel = blockIdx.y;
    const float* S8  = rel ? S8n : S8l;
    const float* Xr  = rel ? xnode : xlink;
    const float* deg = rel ? dgn : dgl;
    const float* Ws  = Wstack + (size_t)rel * 384 * H;
    const float* bmp = bmpAll + rel * H;
    const float* bu  = rel ? bu_ln : bu_nl;
    float* Out = rel ? outn : outl;

    __shared__ float At[24][BM + 4];
    __shared__ float Bt[24][H];
    int tid = threadIdx.x;
    int rowg = tid >> 4;
    int colg = tid & 15;
    int m0 = blockIdx.x * BM;

#pragma unroll
    for (int p = 0; p < 6; ++p) {
        int lin = tid + p * 256;
        int r = lin / 24, k = lin % 24;
        int row = m0 + r;
        float v = 0.f;
        if (row < M) {
            if (k < 8)       v = S8[row * FR + k];
            else if (k < 16) v = deg[row] * Xr[(size_t)row * FR + (k - 8)];
            else             v = Xr[(size_t)row * FR + (k - 16)];
        }
        At[k][r] = v;
    }
#pragma unroll
    for (int p = 0; p < 12; ++p) {
        int lin = tid + p * 256;
        int kk = lin >> 7, c = lin & 127;
        int srcrow = (kk >> 3) * 128 + (kk & 7);
        Bt[kk][c] = Ws[srcrow * H + c];
    }
    __syncthreads();

    float acc[4][8] = {};
#pragma unroll
    for (int kk = 0; kk < 24; ++kk) {
        float a[4], b[8];
        *(float4*)a = *(const float4*)(&At[kk][rowg * 4]);
        *(float4*)(b)     = *(const float4*)(&Bt[kk][colg * 4]);
        *(float4*)(b + 4) = *(const float4*)(&Bt[kk][64 + colg * 4]);
#pragma unroll
        for (int i = 0; i < 4; ++i)
#pragma unroll
            for (int j = 0; j < 8; ++j)
                acc[i][j] += a[i] * b[j];
    }

    int c0 = colg * 4, c1 = 64 + colg * 4;
    float bm0[4], bm1[4], bb0[4], bb1[4];
#pragma unroll
    for (int j = 0; j < 4; ++j) {
        bm0[j] = bmp[c0 + j]; bm1[j] = bmp[c1 + j];
        bb0[j] = bu[c0 + j];  bb1[j] = bu[c1 + j];
    }
#pragma unroll
    for (int i = 0; i < 4; ++i) {
        int row = m0 + rowg * 4 + i;
        if (row < M) {
            float d = deg[row];
            float o0[4], o1[4];
#pragma unroll
            for (int j = 0; j < 4; ++j) {
                o0[j] = fmaxf(acc[i][j]     + d * bm0[j] + bb0[j], 0.f);
                o1[j] = fmaxf(acc[i][j + 4] + d * bm1[j] + bb1[j], 0.f);
            }
            *(float4*)(Out + (size_t)row * H + c0) = *(float4*)o0;
            *(float4*)(Out + (size_t)row * H + c1) = *(float4*)o1;
        }
    }
}

// ---------------- global mean pool ----------------
#define PR 256
__global__ void pool_sum(const float* __restrict__ xl, const int* __restrict__ batch,
                         float* __restrict__ sums) {
    int base = blockIdx.x * PR;
    int col = threadIdx.x & 127;
    int half = threadIdx.x >> 7;
    int rows = min(PR, NL - base);
    float acc = 0.f;
    int cur = -1;
    for (int r = half; r < rows; r += 2) {
        int row = base + r;
        int g = batch[row];
        if (g != cur) {
            if (cur >= 0) atomicAdd(&sums[cur * H + col], acc);
            acc = 0.f;
            cur = g;
        }
        acc += xl[(size_t)row * H + col];
    }
    if (cur >= 0) atomicAdd(&sums[cur * H + col], acc);
}

__global__ void pool_counts(const int* __restrict__ batch, float* __restrict__ cnt) {
    int g = threadIdx.x;
    if (g >= NG) return;
    int lo = 0, hi = NL;
    while (lo < hi) { int mid = (lo + hi) >> 1; if (batch[mid] < g) lo = mid + 1; else hi = mid; }
    int first = lo;
    lo = 0; hi = NL;
    while (lo < hi) { int mid = (lo + hi) >> 1; if (batch[mid] < g + 1) lo = mid + 1; else hi = mid; }
    cnt[g] = (float)(lo - first);
}

__global__ void pool_final(const float* __restrict__ sums, const float* __restrict__ cnt,
                           float* __restrict__ out) {
    int idx = blockIdx.x * blockDim.x + threadIdx.x;
    int g = idx / H;
    out[idx] = sums[idx] / fmaxf(cnt[g], 1.f);
}

static inline size_t rup(size_t n) { return (n + 15) & ~(size_t)15; }

extern "C" void kernel_launch(void* const* d_in, const int* in_sizes, int n_in,
                              void* d_out, int out_size, void* d_ws, size_t ws_size,
                              hipStream_t stream) {
    const float* x_node = (const float*)d_in[0];
    const float* x_link = (const float*)d_in[1];
    const float* Wm_nl  = (const float*)d_in[2];
    const float* bm_nl  = (const float*)d_in[3];
    const float* Wu_nl  = (const float*)d_in[4];
    const float* bu_nl  = (const float*)d_in[5];
    const float* Wm_ln  = (const float*)d_in[6];
    const float* bm_ln  = (const float*)d_in[7];
    const float* Wu_ln  = (const float*)d_in[8];
    const float* bu_ln  = (const float*)d_in[9];
    const int* nl_edge  = (const int*)d_in[10];
    const int* ln_edge  = (const int*)d_in[11];
    const int* batch_link = (const int*)d_in[12];
    (void)in_sizes; (void)n_in; (void)out_size; (void)ws_size;

    char* wsb = (char*)d_ws;
    size_t o = 0;
    auto alloc = [&](size_t elems) { void* p = wsb + o * 4; o += rup(elems); return p; };
    float* xn    = (float*)alloc((size_t)NN * H);
    float* xl    = (float*)alloc((size_t)NL * H);
    float* Sl    = (float*)alloc((size_t)NL * H);   // doubles as S8l (layer 1)
    float* Sn    = (float*)alloc((size_t)NN * H);   // doubles as S8n (layer 1)
    float* deg_l = (float*)alloc(NL);
    float* deg_n = (float*)alloc(NN);
    int*   idl   = (int*)alloc(NL);
    int*   idn   = (int*)alloc(NN);
    int*   offL  = (int*)alloc(NL + 1);
    int*   offN  = (int*)alloc(NN + 1);
    int*   curL  = (int*)alloc(NL);
    int*   curN  = (int*)alloc(NN);
    int*   adjL  = (int*)alloc(NE);
    int*   adjN  = (int*)alloc(NE);
    float* Wstack= (float*)alloc(4L * 384 * H);
    float* bmp   = (float*)alloc(4 * H);
    float* sums  = (float*)alloc(NG * H);
    float* cnt   = (float*)alloc(NG);
    int*   bsum  = (int*)alloc(2 * SNB);
    int*   bbase = (int*)alloc(2 * SNB);

    hipMemsetAsync(idl, 0, (size_t)(rup(NL) + NN) * sizeof(int), stream);
    hipMemsetAsync(sums, 0, (size_t)NG * H * sizeof(float), stream);

    precompute_w<<<(4 * (384 * H + H) + 255) / 256, 256, 0, stream>>>(
        Wm_nl, bm_nl, Wu_nl, Wm_ln, bm_ln, Wu_ln, Wstack, bmp);
    compute_deg<<<(NE + 255) / 256, 256, 0, stream>>>(nl_edge, ln_edge, idl, idn);
    scan1<<<2 * SNB, 256, 0, stream>>>(idl, idn, bsum);
    scan2<<<1, 128, 0, stream>>>(bsum, bbase);
    scan3<<<2 * SNB, 256, 0, stream>>>(idl, idn, bbase, offL, offN, curL, curN, deg_l, deg_n);
    fill_csr<<<(NE + 255) / 256, 256, 0, stream>>>(nl_edge, ln_edge, curL, curN, adjL, adjN);
    pool_counts<<<1, 64, 0, stream>>>(batch_link, cnt);

    // ---- layer 1 ----
    gather_sum8_2<<<dim3((NL * FR + 255) / 256, 2), 256, 0, stream>>>(
        offL, adjL, x_node, Sl, offN, adjN, x_link, Sn);
    gemm_update_l1_2<<<dim3((NL + BM - 1) / BM, 2), 256, 0, stream>>>(
        Sl, x_link, deg_l, Sn, x_node, deg_n, Wstack, bmp, bu_nl, bu_ln, xl, xn, NL);

    // ---- layer 2 ----
    gather_sum2<<<dim3((NL + 7) / 8, 2), 256, 0, stream>>>(
        offL, adjL, xn, Sl, offN, adjN, xl, Sn);
    gemm_update4<<<dim3((NL + GBM - 1) / GBM, 2), 256, 0, stream>>>(
        Sl, xl, deg_l, Sn, xn, deg_n, Wstack, bmp, bu_nl, bu_ln, xl, xn, NL);

    pool_sum<<<(NL + PR - 1) / PR, 256, 0, stream>>>(xl, batch_link, sums);
    pool_final<<<(NG * H) / 256, 256, 0, stream>>>(sums, cnt, (float*)d_out);
}

// Round 7
// 346.176 us; speedup vs baseline: 1.3109x; 1.3109x over previous
//
#include <hip/hip_runtime.h>

// HeteroGNN fused implementation, round 7.
// Algebra: new = relu( S @ W1 + deg.*(x @ W2) + x @ W3 + deg.*bmp + bu )
// Round-7: layer-2 GEMM -> MFMA bf16 (16x16x32), 128x128 tile, BK=32,
// 4 waves 2x2, A staged fp32->bf16 (deg fused), B pre-converted to bf16
// per-tile layout in precompute. fp32 epilogue (deg*bmp + bu + relu).
// fp32 VALU GEMM ceiling was ~60TF (r5: 163us); MFMA path targets ~45us.

#define H 128
#define NN 50000
#define NL 50000
#define NE 400000
#define NG 64
#define FR 8
#define SNB 49

typedef __attribute__((ext_vector_type(8))) short bf16x8;
typedef __attribute__((ext_vector_type(4))) float f32x4;

__device__ __forceinline__ ushort f2bf(float f) {
    union { float f; unsigned u; } v; v.f = f;
    unsigned r = v.u + 0x7FFFu + ((v.u >> 16) & 1u);   // RNE
    return (ushort)(r >> 16);
}

// ---------------- weight fusion (+ bf16 per-tile layout for layer-2) ----------------
// Wstack[combo][384][128] fp32 (combos 0,1 used by layer-1 GEMM).
// WbLin[rel][12 tiles][128 c][32 kt] bf16 for layer-2 MFMA staging.
__global__ void precompute_w(const float* __restrict__ Wm_nl, const float* __restrict__ bm_nl,
                             const float* __restrict__ Wu_nl,
                             const float* __restrict__ Wm_ln, const float* __restrict__ bm_ln,
                             const float* __restrict__ Wu_ln,
                             float* __restrict__ Wstack, float* __restrict__ bmp,
                             ushort* __restrict__ WbLin) {
    int idx = blockIdx.x * blockDim.x + threadIdx.x;
    const int per = 384 * H + H;
    int c = idx / per, r = idx % per;
    if (c >= 4) return;
    int l = c >> 1, rel = c & 1;
    const float* Wm = (rel ? Wm_ln : Wm_nl) + l * 256 * H;
    const float* Wu = (rel ? Wu_ln : Wu_nl) + l * 256 * H;
    const float* bm = (rel ? bm_ln : bm_nl) + l * H;
    float* Ws = Wstack + c * 384 * H;
    if (r < 384 * H) {
        int t = r / H, j = r % H;
        float val;
        if (t < 256) {
            float acc = 0.f;
            for (int k = 0; k < H; ++k) acc += Wm[t * H + k] * Wu[k * H + j];
            val = acc;
        } else {
            val = Wu[(t - 128) * H + j];
        }
        Ws[t * H + j] = val;
        if (c >= 2) {
            // per-tile layout: tile = t>>5, within: [j][t&31]
            WbLin[(size_t)(c - 2) * (12 * 4096) + (size_t)(t >> 5) * 4096 + j * 32 + (t & 31)]
                = f2bf(val);
        }
    } else {
        int j = r - 384 * H;
        float acc = 0.f;
        for (int k = 0; k < H; ++k) acc += bm[k] * Wu[k * H + j];
        bmp[c * H + j] = acc;
    }
}

// ---------------- degree (int) ----------------
__global__ void compute_deg(const int* __restrict__ nl, const int* __restrict__ ln,
                            int* __restrict__ dl, int* __restrict__ dn) {
    int e = blockIdx.x * blockDim.x + threadIdx.x;
    if (e < NE) {
        atomicAdd(&dl[nl[NE + e]], 1);
        atomicAdd(&dn[ln[NE + e]], 1);
    }
}

// ---------------- 3-phase parallel scan ----------------
__global__ void scan1(const int* __restrict__ degL, const int* __restrict__ degN,
                      int* __restrict__ bsum) {
    int arr = blockIdx.x / SNB, blk = blockIdx.x % SNB;
    const int* deg = arr ? degN : degL;
    int tid = threadIdx.x;
    int base = blk * 1024 + tid * 4;
    int s = 0;
#pragma unroll
    for (int i = 0; i < 4; ++i) { int idx = base + i; if (idx < NL) s += deg[idx]; }
    __shared__ int red[256];
    red[tid] = s;
    __syncthreads();
    for (int d = 128; d > 0; d >>= 1) {
        if (tid < d) red[tid] += red[tid + d];
        __syncthreads();
    }
    if (tid == 0) bsum[blockIdx.x] = red[0];
}

__global__ void scan2(const int* __restrict__ bsum, int* __restrict__ bbase) {
    __shared__ int sh[128];
    int tid = threadIdx.x;
    int v0 = (tid < 2 * SNB) ? bsum[tid] : 0;
    sh[tid] = v0;
    __syncthreads();
    int gstart = (tid < SNB) ? 0 : SNB;
    for (int d = 1; d < 64; d <<= 1) {
        int v = (tid >= gstart + d && tid < 2 * SNB) ? sh[tid - d] : 0;
        __syncthreads();
        sh[tid] += v;
        __syncthreads();
    }
    if (tid < 2 * SNB) bbase[tid] = sh[tid] - v0;
}

__global__ void scan3(const int* __restrict__ degL, const int* __restrict__ degN,
                      const int* __restrict__ bbase,
                      int* __restrict__ offL, int* __restrict__ offN,
                      int* __restrict__ curL, int* __restrict__ curN,
                      float* __restrict__ fdegL, float* __restrict__ fdegN) {
    int arr = blockIdx.x / SNB, blk = blockIdx.x % SNB;
    const int* deg = arr ? degN : degL;
    int* off = arr ? offN : offL;
    int* cur = arr ? curN : curL;
    float* fdeg = arr ? fdegN : fdegL;
    int tid = threadIdx.x;
    int base = blk * 1024 + tid * 4;
    int d4[4]; int s = 0;
#pragma unroll
    for (int i = 0; i < 4; ++i) {
        int idx = base + i;
        d4[i] = (idx < NL) ? deg[idx] : 0;
        s += d4[i];
    }
    __shared__ int part[256];
    part[tid] = s;
    __syncthreads();
    for (int d = 1; d < 256; d <<= 1) {
        int v = (tid >= d) ? part[tid - d] : 0;
        __syncthreads();
        part[tid] += v;
        __syncthreads();
    }
    int run = bbase[blockIdx.x] + part[tid] - s;
#pragma unroll
    for (int i = 0; i < 4; ++i) {
        int idx = base + i;
        if (idx < NL) {
            off[idx] = run; cur[idx] = run; fdeg[idx] = (float)d4[i];
            run += d4[i];
            if (idx == NL - 1) off[NL] = run;
        }
    }
}

// ---------------- CSR fill ----------------
__global__ void fill_csr(const int* __restrict__ nl, const int* __restrict__ ln,
                         int* __restrict__ curL, int* __restrict__ curN,
                         int* __restrict__ adjL, int* __restrict__ adjN) {
    int e = blockIdx.x * blockDim.x + threadIdx.x;
    if (e >= NE) return;
    {
        int src = nl[e], dst = nl[NE + e];
        int p = atomicAdd(&curL[dst], 1);
        adjL[p] = src;
    }
    {
        int src = ln[e], dst = ln[NE + e];
        int p = atomicAdd(&curN[dst], 1);
        adjN[p] = src;
    }
}

// ---------------- layer-1 gather (raw 8-col), both relations ----------------
__launch_bounds__(256)
__global__ void gather_sum8_2(const int* __restrict__ offL, const int* __restrict__ adjL,
                              const float* __restrict__ xnode, float* __restrict__ S8l,
                              const int* __restrict__ offN, const int* __restrict__ adjN,
                              const float* __restrict__ xlink, float* __restrict__ S8n) {
    int rel = blockIdx.y;
    const int* off = rel ? offN : offL;
    const int* adj = rel ? adjN : adjL;
    const float* Xr = rel ? xlink : xnode;
    float* S8 = rel ? S8n : S8l;
    int t = blockIdx.x * 256 + threadIdx.x;
    int row = t >> 3, c = t & 7;
    if (row >= NL) return;
    int beg = off[row], end = off[row + 1];
    float acc = 0.f;
    for (int i = beg; i < end; ++i)
        acc += Xr[(size_t)adj[i] * FR + c];
    S8[row * FR + c] = acc;
}

// ---------------- layer-2 gather, both relations, 32-lane float4 rows ----------------
__launch_bounds__(256)
__global__ void gather_sum2(const int* __restrict__ offL, const int* __restrict__ adjL,
                            const float* __restrict__ xnp, float* __restrict__ Sl,
                            const int* __restrict__ offN, const int* __restrict__ adjN,
                            const float* __restrict__ xlp, float* __restrict__ Sn) {
    int rel = blockIdx.y;
    const int* off = rel ? offN : offL;
    const int* adj = rel ? adjN : adjL;
    const float* X = rel ? xlp : xnp;
    float* Sg = rel ? Sn : Sl;
    int row = blockIdx.x * 8 + (threadIdx.x >> 5);
    int lane = threadIdx.x & 31;
    if (row >= NL) return;
    int beg = off[row], end = off[row + 1];
    float ax = 0.f, ay = 0.f, az = 0.f, aw = 0.f;
    float bx = 0.f, by = 0.f, bz = 0.f, bw = 0.f;
    int i = beg;
    for (; i + 1 < end; i += 2) {
        float4 a = *(const float4*)(X + (size_t)adj[i] * H + lane * 4);
        float4 b = *(const float4*)(X + (size_t)adj[i + 1] * H + lane * 4);
        ax += a.x; ay += a.y; az += a.z; aw += a.w;
        bx += b.x; by += b.y; bz += b.z; bw += b.w;
    }
    if (i < end) {
        float4 a = *(const float4*)(X + (size_t)adj[i] * H + lane * 4);
        ax += a.x; ay += a.y; az += a.z; aw += a.w;
    }
    float4 r = make_float4(ax + bx, ay + by, az + bz, aw + bw);
    *(float4*)(Sg + (size_t)row * H + lane * 4) = r;
}

// ---------------- layer-2 fused GEMM via MFMA bf16, both relations ----------------
// Out = relu([S | deg.*X | X]_bf16 @ W_bf16 + deg.*bmp + bu), fp32 accumulate.
// 128x128 tile, BK=32, 4 waves (2x2), 4x4 16x16 frags per wave.
#define LSTR 40   // LDS row stride in bf16 elems (80 B, 16B-aligned, 2-way banks)
__launch_bounds__(256)
__global__ void gemm_mfma(const float* __restrict__ Sl, const float* __restrict__ xlp,
                          const float* __restrict__ dgl,
                          const float* __restrict__ Sn, const float* __restrict__ xnp,
                          const float* __restrict__ dgn,
                          const ushort* __restrict__ WbLin, const float* __restrict__ bmpAll,
                          const float* __restrict__ bu_nl, const float* __restrict__ bu_ln,
                          float* __restrict__ outl, float* __restrict__ outn, int M) {
    int rel = blockIdx.y;
    const float* S   = rel ? Sn : Sl;
    const float* X   = rel ? xnp : xlp;
    const float* deg = rel ? dgn : dgl;
    const ushort* Wb = WbLin + (size_t)rel * (12 * 4096);
    const float* bmp = bmpAll + (2 + rel) * H;
    const float* bu  = (rel ? bu_ln : bu_nl) + H;   // layer index 1
    float* Out = rel ? outn : outl;

    __shared__ ushort A_lds[128 * LSTR];
    __shared__ ushort B_lds[128 * LSTR];

    int tid = threadIdx.x;
    int lane = tid & 63;
    int wave = tid >> 6;
    int wm = wave >> 1, wn = wave & 1;
    int m0 = blockIdx.x * 128;

    // A staging mapping: thread covers rows arow+32p (p=0..3), k-chunk kq*4
    int arow = tid >> 3;
    int kq = tid & 7;
    float dpre[4];
    bool vrow[4];
#pragma unroll
    for (int p = 0; p < 4; ++p) {
        int grow = m0 + arow + 32 * p;
        vrow[p] = grow < M;
        dpre[p] = vrow[p] ? deg[grow] : 0.f;
    }
    // B staging mapping: thread covers col bc, k-half bh*16
    int bc = tid >> 1;
    int bh = tid & 1;

    f32x4 acc[4][4];
#pragma unroll
    for (int i = 0; i < 4; ++i)
#pragma unroll
        for (int j = 0; j < 4; ++j)
            acc[i][j] = (f32x4){0.f, 0.f, 0.f, 0.f};

    int lrow = lane & 15, lg = lane >> 4;

    for (int kt = 0; kt < 12; ++kt) {
        int k0 = kt * 32;
        int piece = k0 >> 7;                  // 0:S 1:deg*X 2:X
        const float* Asrc = (piece == 0) ? S : X;
        int kin = (k0 & 127) + kq * 4;
        // ---- stage A (fp32 -> bf16, deg fused) ----
#pragma unroll
        for (int p = 0; p < 4; ++p) {
            int row = arow + 32 * p;
            float4 v = make_float4(0.f, 0.f, 0.f, 0.f);
            if (vrow[p]) v = *(const float4*)(Asrc + (size_t)(m0 + row) * H + kin);
            if (piece == 1) {
                float d = dpre[p];
                v.x *= d; v.y *= d; v.z *= d; v.w *= d;
            }
            uint2 w;
            w.x = (unsigned)f2bf(v.x) | ((unsigned)f2bf(v.y) << 16);
            w.y = (unsigned)f2bf(v.z) | ((unsigned)f2bf(v.w) << 16);
            *(uint2*)&A_lds[row * LSTR + kq * 4] = w;
        }
        // ---- stage B (pre-laid-out bf16 copy) ----
        {
            const uint4* src = (const uint4*)(Wb + (size_t)kt * 4096 + bc * 32 + bh * 16);
            uint4 b0 = src[0];
            *(uint4*)&B_lds[bc * LSTR + bh * 16 + 0] = b0;
            // second 8 bf16 of this 16-chunk come from src+... (16 bf16 per thread = 2 x uint4)
        }
        {
            const uint4* src = (const uint4*)(Wb + (size_t)kt * 4096 + bc * 32 + bh * 16 + 8);
            uint4 b1 = src[0];
            *(uint4*)&B_lds[bc * LSTR + bh * 16 + 8] = b1;
        }
        __syncthreads();

        // ---- fragments + MFMA ----
        bf16x8 af[4], bf[4];
#pragma unroll
        for (int mf = 0; mf < 4; ++mf)
            af[mf] = *(const bf16x8*)&A_lds[(wm * 64 + mf * 16 + lrow) * LSTR + lg * 8];
#pragma unroll
        for (int nf = 0; nf < 4; ++nf)
            bf[nf] = *(const bf16x8*)&B_lds[(wn * 64 + nf * 16 + lrow) * LSTR + lg * 8];
#pragma unroll
        for (int mf = 0; mf < 4; ++mf)
#pragma unroll
            for (int nf = 0; nf < 4; ++nf)
                acc[mf][nf] = __builtin_amdgcn_mfma_f32_16x16x32_bf16(
                    af[mf], bf[nf], acc[mf][nf], 0, 0, 0);
        __syncthreads();
    }

    // ---- epilogue: C[row][col], col = wn*64+nf*16+lrow, row = m0+wm*64+mf*16+lg*4+r ----
    float bmpv[4], buv[4];
#pragma unroll
    for (int nf = 0; nf < 4; ++nf) {
        int col = wn * 64 + nf * 16 + lrow;
        bmpv[nf] = bmp[col];
        buv[nf] = bu[col];
    }
#pragma unroll
    for (int mf = 0; mf < 4; ++mf) {
#pragma unroll
        for (int r = 0; r < 4; ++r) {
            int row = m0 + wm * 64 + mf * 16 + lg * 4 + r;
            if (row < M) {
                float d = deg[row];
#pragma unroll
                for (int nf = 0; nf < 4; ++nf) {
                    int col = wn * 64 + nf * 16 + lrow;
                    float v = acc[mf][nf][r] + d * bmpv[nf] + buv[nf];
                    Out[(size_t)row * H + col] = fmaxf(v, 0.f);
                }
            }
        }
    }
}

// ---------------- layer-1 fused GEMM (K=24), both relations ----------------
#define BM 64
__launch_bounds__(256)
__global__ void gemm_update_l1_2(const float* __restrict__ S8l, const float* __restrict__ xlink,
                                 const float* __restrict__ dgl,
                                 const float* __restrict__ S8n, const float* __restrict__ xnode,
                                 const float* __restrict__ dgn,
                                 const float* __restrict__ Wstack, const float* __restrict__ bmpAll,
                                 const float* __restrict__ bu_nl, const float* __restrict__ bu_ln,
                                 float* __restrict__ outl, float* __restrict__ outn, int M) {
    int rel = blockIdx.y;
    const float* S8  = rel ? S8n : S8l;
    const float* Xr  = rel ? xnode : xlink;
    const float* deg = rel ? dgn : dgl;
    const float* Ws  = Wstack + (size_t)rel * 384 * H;
    const float* bmp = bmpAll + rel * H;
    const float* bu  = rel ? bu_ln : bu_nl;
    float* Out = rel ? outn : outl;

    __shared__ float At[24][BM + 4];
    __shared__ float Bt[24][H];
    int tid = threadIdx.x;
    int rowg = tid >> 4;
    int colg = tid & 15;
    int m0 = blockIdx.x * BM;

#pragma unroll
    for (int p = 0; p < 6; ++p) {
        int lin = tid + p * 256;
        int r = lin / 24, k = lin % 24;
        int row = m0 + r;
        float v = 0.f;
        if (row < M) {
            if (k < 8)       v = S8[row * FR + k];
            else if (k < 16) v = deg[row] * Xr[(size_t)row * FR + (k - 8)];
            else             v = Xr[(size_t)row * FR + (k - 16)];
        }
        At[k][r] = v;
    }
#pragma unroll
    for (int p = 0; p < 12; ++p) {
        int lin = tid + p * 256;
        int kk = lin >> 7, c = lin & 127;
        int srcrow = (kk >> 3) * 128 + (kk & 7);
        Bt[kk][c] = Ws[srcrow * H + c];
    }
    __syncthreads();

    float acc[4][8] = {};
#pragma unroll
    for (int kk = 0; kk < 24; ++kk) {
        float a[4], b[8];
        *(float4*)a = *(const float4*)(&At[kk][rowg * 4]);
        *(float4*)(b)     = *(const float4*)(&Bt[kk][colg * 4]);
        *(float4*)(b + 4) = *(const float4*)(&Bt[kk][64 + colg * 4]);
#pragma unroll
        for (int i = 0; i < 4; ++i)
#pragma unroll
            for (int j = 0; j < 8; ++j)
                acc[i][j] += a[i] * b[j];
    }

    int c0 = colg * 4, c1 = 64 + colg * 4;
    float bm0[4], bm1[4], bb0[4], bb1[4];
#pragma unroll
    for (int j = 0; j < 4; ++j) {
        bm0[j] = bmp[c0 + j]; bm1[j] = bmp[c1 + j];
        bb0[j] = bu[c0 + j];  bb1[j] = bu[c1 + j];
    }
#pragma unroll
    for (int i = 0; i < 4; ++i) {
        int row = m0 + rowg * 4 + i;
        if (row < M) {
            float d = deg[row];
            float o0[4], o1[4];
#pragma unroll
            for (int j = 0; j < 4; ++j) {
                o0[j] = fmaxf(acc[i][j]     + d * bm0[j] + bb0[j], 0.f);
                o1[j] = fmaxf(acc[i][j + 4] + d * bm1[j] + bb1[j], 0.f);
            }
            *(float4*)(Out + (size_t)row * H + c0) = *(float4*)o0;
            *(float4*)(Out + (size_t)row * H + c1) = *(float4*)o1;
        }
    }
}

// ---------------- global mean pool ----------------
#define PR 256
__global__ void pool_sum(const float* __restrict__ xl, const int* __restrict__ batch,
                         float* __restrict__ sums) {
    int base = blockIdx.x * PR;
    int col = threadIdx.x & 127;
    int half = threadIdx.x >> 7;
    int rows = min(PR, NL - base);
    float acc = 0.f;
    int cur = -1;
    for (int r = half; r < rows; r += 2) {
        int row = base + r;
        int g = batch[row];
        if (g != cur) {
            if (cur >= 0) atomicAdd(&sums[cur * H + col], acc);
            acc = 0.f;
            cur = g;
        }
        acc += xl[(size_t)row * H + col];
    }
    if (cur >= 0) atomicAdd(&sums[cur * H + col], acc);
}

__global__ void pool_counts(const int* __restrict__ batch, float* __restrict__ cnt) {
    int g = threadIdx.x;
    if (g >= NG) return;
    int lo = 0, hi = NL;
    while (lo < hi) { int mid = (lo + hi) >> 1; if (batch[mid] < g) lo = mid + 1; else hi = mid; }
    int first = lo;
    lo = 0; hi = NL;
    while (lo < hi) { int mid = (lo + hi) >> 1; if (batch[mid] < g + 1) lo = mid + 1; else hi = mid; }
    cnt[g] = (float)(lo - first);
}

__global__ void pool_final(const float* __restrict__ sums, const float* __restrict__ cnt,
                           float* __restrict__ out) {
    int idx = blockIdx.x * blockDim.x + threadIdx.x;
    int g = idx / H;
    out[idx] = sums[idx] / fmaxf(cnt[g], 1.f);
}

static inline size_t rup(size_t n) { return (n + 15) & ~(size_t)15; }

extern "C" void kernel_launch(void* const* d_in, const int* in_sizes, int n_in,
                              void* d_out, int out_size, void* d_ws, size_t ws_size,
                              hipStream_t stream) {
    const float* x_node = (const float*)d_in[0];
    const float* x_link = (const float*)d_in[1];
    const float* Wm_nl  = (const float*)d_in[2];
    const float* bm_nl  = (const float*)d_in[3];
    const float* Wu_nl  = (const float*)d_in[4];
    const float* bu_nl  = (const float*)d_in[5];
    const float* Wm_ln  = (const float*)d_in[6];
    const float* bm_ln  = (const float*)d_in[7];
    const float* Wu_ln  = (const float*)d_in[8];
    const float* bu_ln  = (const float*)d_in[9];
    const int* nl_edge  = (const int*)d_in[10];
    const int* ln_edge  = (const int*)d_in[11];
    const int* batch_link = (const int*)d_in[12];
    (void)in_sizes; (void)n_in; (void)out_size; (void)ws_size;

    char* wsb = (char*)d_ws;
    size_t o = 0;
    auto alloc = [&](size_t elems) { void* p = wsb + o * 4; o += rup(elems); return p; };
    float* xn    = (float*)alloc((size_t)NN * H);
    float* xl    = (float*)alloc((size_t)NL * H);
    float* Sl    = (float*)alloc((size_t)NL * H);   // doubles as S8l (layer 1)
    float* Sn    = (float*)alloc((size_t)NN * H);   // doubles as S8n (layer 1)
    float* deg_l = (float*)alloc(NL);
    float* deg_n = (float*)alloc(NN);
    int*   idl   = (int*)alloc(NL);
    int*   idn   = (int*)alloc(NN);
    int*   offL  = (int*)alloc(NL + 1);
    int*   offN  = (int*)alloc(NN + 1);
    int*   curL  = (int*)alloc(NL);
    int*   curN  = (int*)alloc(NN);
    int*   adjL  = (int*)alloc(NE);
    int*   adjN  = (int*)alloc(NE);
    float* Wstack= (float*)alloc(4L * 384 * H);
    float* bmp   = (float*)alloc(4 * H);
    float* sums  = (float*)alloc(NG * H);
    float* cnt   = (float*)alloc(NG);
    int*   bsum  = (int*)alloc(2 * SNB);
    int*   bbase = (int*)alloc(2 * SNB);
    ushort* WbLin= (ushort*)alloc(2 * 12 * 4096 / 2);   // bf16: 2 rel x 49152 elems

    hipMemsetAsync(idl, 0, (size_t)(rup(NL) + NN) * sizeof(int), stream);
    hipMemsetAsync(sums, 0, (size_t)NG * H * sizeof(float), stream);

    precompute_w<<<(4 * (384 * H + H) + 255) / 256, 256, 0, stream>>>(
        Wm_nl, bm_nl, Wu_nl, Wm_ln, bm_ln, Wu_ln, Wstack, bmp, WbLin);
    compute_deg<<<(NE + 255) / 256, 256, 0, stream>>>(nl_edge, ln_edge, idl, idn);
    scan1<<<2 * SNB, 256, 0, stream>>>(idl, idn, bsum);
    scan2<<<1, 128, 0, stream>>>(bsum, bbase);
    scan3<<<2 * SNB, 256, 0, stream>>>(idl, idn, bbase, offL, offN, curL, curN, deg_l, deg_n);
    fill_csr<<<(NE + 255) / 256, 256, 0, stream>>>(nl_edge, ln_edge, curL, curN, adjL, adjN);
    pool_counts<<<1, 64, 0, stream>>>(batch_link, cnt);

    // ---- layer 1 ----
    gather_sum8_2<<<dim3((NL * FR + 255) / 256, 2), 256, 0, stream>>>(
        offL, adjL, x_node, Sl, offN, adjN, x_link, Sn);
    gemm_update_l1_2<<<dim3((NL + BM - 1) / BM, 2), 256, 0, stream>>>(
        Sl, x_link, deg_l, Sn, x_node, deg_n, Wstack, bmp, bu_nl, bu_ln, xl, xn, NL);

    // ---- layer 2 ----
    gather_sum2<<<dim3((NL + 7) / 8, 2), 256, 0, stream>>>(
        offL, adjL, xn, Sl, offN, adjN, xl, Sn);
    gemm_mfma<<<dim3((NL + 127) / 128, 2), 256, 0, stream>>>(
        Sl, xl, deg_l, Sn, xn, deg_n, WbLin, bmp, bu_nl, bu_ln, xl, xn, NL);

    pool_sum<<<(NL + PR - 1) / PR, 256, 0, stream>>>(xl, batch_link, sums);
    pool_final<<<(NG * H) / 256, 256, 0, stream>>>(sums, cnt, (float*)d_out);
}

// Round 8
// 286.217 us; speedup vs baseline: 1.5855x; 1.2095x over previous
//
#include <hip/hip_runtime.h>

// HeteroGNN fused implementation, round 8.
// Algebra: new = relu( S @ W1 + deg.*(x @ W2) + x @ W3 + deg.*bmp + bu )
// Round-8: (a) layer-1 GEMM rewritten as direct per-row kernel (was 81us,
// 172 VGPR, 9.7% occ for 0.6 GFLOP); (b) hidden state xn/xl and gathered S
// stored as bf16 (the layer-2 MFMA GEMM already rounds A to bf16 at staging,
// so moving the rounding upstream is error-free and halves gather traffic).

#define H 128
#define NN 50000
#define NL 50000
#define NE 400000
#define NG 64
#define FR 8
#define SNB 49

typedef __attribute__((ext_vector_type(8))) short bf16x8;
typedef __attribute__((ext_vector_type(4))) float f32x4;
typedef unsigned short ushort_t;

__device__ __forceinline__ ushort_t f2bf(float f) {
    union { float f; unsigned u; } v; v.f = f;
    unsigned r = v.u + 0x7FFFu + ((v.u >> 16) & 1u);   // RNE
    return (ushort_t)(r >> 16);
}
__device__ __forceinline__ float bf2f(ushort_t u) {
    union { unsigned u; float f; } v; v.u = ((unsigned)u) << 16; return v.f;
}

// ---------------- weight fusion (+ bf16 per-tile layout for layer-2) ----------------
__global__ void precompute_w(const float* __restrict__ Wm_nl, const float* __restrict__ bm_nl,
                             const float* __restrict__ Wu_nl,
                             const float* __restrict__ Wm_ln, const float* __restrict__ bm_ln,
                             const float* __restrict__ Wu_ln,
                             float* __restrict__ Wstack, float* __restrict__ bmp,
                             ushort_t* __restrict__ WbLin) {
    int idx = blockIdx.x * blockDim.x + threadIdx.x;
    const int per = 384 * H + H;
    int c = idx / per, r = idx % per;
    if (c >= 4) return;
    int l = c >> 1, rel = c & 1;
    const float* Wm = (rel ? Wm_ln : Wm_nl) + l * 256 * H;
    const float* Wu = (rel ? Wu_ln : Wu_nl) + l * 256 * H;
    const float* bm = (rel ? bm_ln : bm_nl) + l * H;
    float* Ws = Wstack + c * 384 * H;
    if (r < 384 * H) {
        int t = r / H, j = r % H;
        float val;
        if (t < 256) {
            float acc = 0.f;
            for (int k = 0; k < H; ++k) acc += Wm[t * H + k] * Wu[k * H + j];
            val = acc;
        } else {
            val = Wu[(t - 128) * H + j];
        }
        Ws[t * H + j] = val;
        if (c >= 2) {
            WbLin[(size_t)(c - 2) * (12 * 4096) + (size_t)(t >> 5) * 4096 + j * 32 + (t & 31)]
                = f2bf(val);
        }
    } else {
        int j = r - 384 * H;
        float acc = 0.f;
        for (int k = 0; k < H; ++k) acc += bm[k] * Wu[k * H + j];
        bmp[c * H + j] = acc;
    }
}

// ---------------- degree (int) ----------------
__global__ void compute_deg(const int* __restrict__ nl, const int* __restrict__ ln,
                            int* __restrict__ dl, int* __restrict__ dn) {
    int e = blockIdx.x * blockDim.x + threadIdx.x;
    if (e < NE) {
        atomicAdd(&dl[nl[NE + e]], 1);
        atomicAdd(&dn[ln[NE + e]], 1);
    }
}

// ---------------- 3-phase parallel scan ----------------
__global__ void scan1(const int* __restrict__ degL, const int* __restrict__ degN,
                      int* __restrict__ bsum) {
    int arr = blockIdx.x / SNB, blk = blockIdx.x % SNB;
    const int* deg = arr ? degN : degL;
    int tid = threadIdx.x;
    int base = blk * 1024 + tid * 4;
    int s = 0;
#pragma unroll
    for (int i = 0; i < 4; ++i) { int idx = base + i; if (idx < NL) s += deg[idx]; }
    __shared__ int red[256];
    red[tid] = s;
    __syncthreads();
    for (int d = 128; d > 0; d >>= 1) {
        if (tid < d) red[tid] += red[tid + d];
        __syncthreads();
    }
    if (tid == 0) bsum[blockIdx.x] = red[0];
}

__global__ void scan2(const int* __restrict__ bsum, int* __restrict__ bbase) {
    __shared__ int sh[128];
    int tid = threadIdx.x;
    int v0 = (tid < 2 * SNB) ? bsum[tid] : 0;
    sh[tid] = v0;
    __syncthreads();
    int gstart = (tid < SNB) ? 0 : SNB;
    for (int d = 1; d < 64; d <<= 1) {
        int v = (tid >= gstart + d && tid < 2 * SNB) ? sh[tid - d] : 0;
        __syncthreads();
        sh[tid] += v;
        __syncthreads();
    }
    if (tid < 2 * SNB) bbase[tid] = sh[tid] - v0;
}

__global__ void scan3(const int* __restrict__ degL, const int* __restrict__ degN,
                      const int* __restrict__ bbase,
                      int* __restrict__ offL, int* __restrict__ offN,
                      int* __restrict__ curL, int* __restrict__ curN,
                      float* __restrict__ fdegL, float* __restrict__ fdegN) {
    int arr = blockIdx.x / SNB, blk = blockIdx.x % SNB;
    const int* deg = arr ? degN : degL;
    int* off = arr ? offN : offL;
    int* cur = arr ? curN : curL;
    float* fdeg = arr ? fdegN : fdegL;
    int tid = threadIdx.x;
    int base = blk * 1024 + tid * 4;
    int d4[4]; int s = 0;
#pragma unroll
    for (int i = 0; i < 4; ++i) {
        int idx = base + i;
        d4[i] = (idx < NL) ? deg[idx] : 0;
        s += d4[i];
    }
    __shared__ int part[256];
    part[tid] = s;
    __syncthreads();
    for (int d = 1; d < 256; d <<= 1) {
        int v = (tid >= d) ? part[tid - d] : 0;
        __syncthreads();
        part[tid] += v;
        __syncthreads();
    }
    int run = bbase[blockIdx.x] + part[tid] - s;
#pragma unroll
    for (int i = 0; i < 4; ++i) {
        int idx = base + i;
        if (idx < NL) {
            off[idx] = run; cur[idx] = run; fdeg[idx] = (float)d4[i];
            run += d4[i];
            if (idx == NL - 1) off[NL] = run;
        }
    }
}

// ---------------- CSR fill ----------------
__global__ void fill_csr(const int* __restrict__ nl, const int* __restrict__ ln,
                         int* __restrict__ curL, int* __restrict__ curN,
                         int* __restrict__ adjL, int* __restrict__ adjN) {
    int e = blockIdx.x * blockDim.x + threadIdx.x;
    if (e >= NE) return;
    {
        int src = nl[e], dst = nl[NE + e];
        int p = atomicAdd(&curL[dst], 1);
        adjL[p] = src;
    }
    {
        int src = ln[e], dst = ln[NE + e];
        int p = atomicAdd(&curN[dst], 1);
        adjN[p] = src;
    }
}

// ---------------- layer-1 gather (raw 8-col), both relations ----------------
__launch_bounds__(256)
__global__ void gather_sum8_2(const int* __restrict__ offL, const int* __restrict__ adjL,
                              const float* __restrict__ xnode, float* __restrict__ S8l,
                              const int* __restrict__ offN, const int* __restrict__ adjN,
                              const float* __restrict__ xlink, float* __restrict__ S8n) {
    int rel = blockIdx.y;
    const int* off = rel ? offN : offL;
    const int* adj = rel ? adjN : adjL;
    const float* Xr = rel ? xlink : xnode;
    float* S8 = rel ? S8n : S8l;
    int t = blockIdx.x * 256 + threadIdx.x;
    int row = t >> 3, c = t & 7;
    if (row >= NL) return;
    int beg = off[row], end = off[row + 1];
    float acc = 0.f;
    for (int i = beg; i < end; ++i)
        acc += Xr[(size_t)adj[i] * FR + c];
    S8[row * FR + c] = acc;
}

// ---------------- layer-1 fused GEMM, direct per-row (K=24) ----------------
// out = relu([S8 | deg*Xr | Xr] @ W24 + deg*bmp + bu), bf16 output.
__launch_bounds__(256)
__global__ void gemm_l1(const float* __restrict__ S8l, const float* __restrict__ xlink,
                        const float* __restrict__ dgl,
                        const float* __restrict__ S8n, const float* __restrict__ xnode,
                        const float* __restrict__ dgn,
                        const float* __restrict__ Wstack, const float* __restrict__ bmpAll,
                        const float* __restrict__ bu_nl, const float* __restrict__ bu_ln,
                        ushort_t* __restrict__ outl, ushort_t* __restrict__ outn) {
    int rel = blockIdx.y;
    const float* S8  = rel ? S8n : S8l;
    const float* Xr  = rel ? xnode : xlink;
    const float* deg = rel ? dgn : dgl;
    const float* Ws  = Wstack + (size_t)rel * 384 * H;
    const float* bmp = bmpAll + rel * H;
    const float* bu  = rel ? bu_ln : bu_nl;
    ushort_t* Out = rel ? outn : outl;

    __shared__ float Wl[24][H];
    __shared__ float bf2[2][H];
    int tid = threadIdx.x;
    for (int p = tid; p < 24 * H; p += 256) {
        int kk = p >> 7, c = p & 127;
        int srcrow = (kk >> 3) * 128 + (kk & 7);
        Wl[kk][c] = Ws[srcrow * H + c];
    }
    if (tid < 128) { bf2[0][tid] = bmp[tid]; bf2[1][tid] = bu[tid]; }
    __syncthreads();

    int rl = tid >> 5;       // 8 rows per block
    int cg = tid & 31;       // 4 cols per thread
    int row = blockIdx.x * 8 + rl;
    if (row >= NL) return;
    float d = deg[row];
    float a[16];
    *(float4*)(a)      = *(const float4*)(S8 + (size_t)row * FR);
    *(float4*)(a + 4)  = *(const float4*)(S8 + (size_t)row * FR + 4);
    *(float4*)(a + 8)  = *(const float4*)(Xr + (size_t)row * FR);
    *(float4*)(a + 12) = *(const float4*)(Xr + (size_t)row * FR + 4);

    int c0 = cg * 4;
    float acc[4] = {0.f, 0.f, 0.f, 0.f};
#pragma unroll
    for (int k = 0; k < 8; ++k) {
        float4 w = *(const float4*)(&Wl[k][c0]);
        float av = a[k];
        acc[0] += av * w.x; acc[1] += av * w.y; acc[2] += av * w.z; acc[3] += av * w.w;
    }
#pragma unroll
    for (int k = 0; k < 8; ++k) {
        float4 w = *(const float4*)(&Wl[8 + k][c0]);
        float av = d * a[8 + k];
        acc[0] += av * w.x; acc[1] += av * w.y; acc[2] += av * w.z; acc[3] += av * w.w;
    }
#pragma unroll
    for (int k = 0; k < 8; ++k) {
        float4 w = *(const float4*)(&Wl[16 + k][c0]);
        float av = a[8 + k];
        acc[0] += av * w.x; acc[1] += av * w.y; acc[2] += av * w.z; acc[3] += av * w.w;
    }
    uint2 o;
    {
        float v0 = fmaxf(acc[0] + d * bf2[0][c0 + 0] + bf2[1][c0 + 0], 0.f);
        float v1 = fmaxf(acc[1] + d * bf2[0][c0 + 1] + bf2[1][c0 + 1], 0.f);
        float v2 = fmaxf(acc[2] + d * bf2[0][c0 + 2] + bf2[1][c0 + 2], 0.f);
        float v3 = fmaxf(acc[3] + d * bf2[0][c0 + 3] + bf2[1][c0 + 3], 0.f);
        o.x = (unsigned)f2bf(v0) | ((unsigned)f2bf(v1) << 16);
        o.y = (unsigned)f2bf(v2) | ((unsigned)f2bf(v3) << 16);
    }
    *(uint2*)(Out + (size_t)row * H + c0) = o;
}

// ---------------- layer-2 gather (bf16 in, fp32 accum, bf16 out) ----------------
__launch_bounds__(256)
__global__ void gather_bf(const int* __restrict__ offL, const int* __restrict__ adjL,
                          const ushort_t* __restrict__ xnb, ushort_t* __restrict__ Sbl,
                          const int* __restrict__ offN, const int* __restrict__ adjN,
                          const ushort_t* __restrict__ xlb, ushort_t* __restrict__ Sbn) {
    int rel = blockIdx.y;
    const int* off = rel ? offN : offL;
    const int* adj = rel ? adjN : adjL;
    const ushort_t* X = rel ? xlb : xnb;
    ushort_t* Sg = rel ? Sbn : Sbl;
    int row = blockIdx.x * 8 + (threadIdx.x >> 5);
    int lane = threadIdx.x & 31;
    if (row >= NL) return;
    int beg = off[row], end = off[row + 1];
    float a0 = 0.f, a1 = 0.f, a2 = 0.f, a3 = 0.f;
    float b0 = 0.f, b1 = 0.f, b2 = 0.f, b3 = 0.f;
    int i = beg;
    for (; i + 1 < end; i += 2) {
        uint2 ua = *(const uint2*)(X + (size_t)adj[i] * H + lane * 4);
        uint2 ub = *(const uint2*)(X + (size_t)adj[i + 1] * H + lane * 4);
        a0 += bf2f((ushort_t)(ua.x & 0xFFFF)); a1 += bf2f((ushort_t)(ua.x >> 16));
        a2 += bf2f((ushort_t)(ua.y & 0xFFFF)); a3 += bf2f((ushort_t)(ua.y >> 16));
        b0 += bf2f((ushort_t)(ub.x & 0xFFFF)); b1 += bf2f((ushort_t)(ub.x >> 16));
        b2 += bf2f((ushort_t)(ub.y & 0xFFFF)); b3 += bf2f((ushort_t)(ub.y >> 16));
    }
    if (i < end) {
        uint2 ua = *(const uint2*)(X + (size_t)adj[i] * H + lane * 4);
        a0 += bf2f((ushort_t)(ua.x & 0xFFFF)); a1 += bf2f((ushort_t)(ua.x >> 16));
        a2 += bf2f((ushort_t)(ua.y & 0xFFFF)); a3 += bf2f((ushort_t)(ua.y >> 16));
    }
    uint2 o;
    o.x = (unsigned)f2bf(a0 + b0) | ((unsigned)f2bf(a1 + b1) << 16);
    o.y = (unsigned)f2bf(a2 + b2) | ((unsigned)f2bf(a3 + b3) << 16);
    *(uint2*)(Sg + (size_t)row * H + lane * 4) = o;
}

// ---------------- layer-2 fused GEMM via MFMA bf16 (bf16 state) ----------------
#define LSTR 40
__launch_bounds__(256)
__global__ void gemm_mfma(const ushort_t* __restrict__ Sbl, const ushort_t* __restrict__ xlb,
                          const float* __restrict__ dgl,
                          const ushort_t* __restrict__ Sbn, const ushort_t* __restrict__ xnb,
                          const float* __restrict__ dgn,
                          const ushort_t* __restrict__ WbLin, const float* __restrict__ bmpAll,
                          const float* __restrict__ bu_nl, const float* __restrict__ bu_ln,
                          ushort_t* __restrict__ outl, ushort_t* __restrict__ outn, int M) {
    int rel = blockIdx.y;
    const ushort_t* S  = rel ? Sbn : Sbl;
    const ushort_t* X  = rel ? xnb : xlb;
    const float* deg = rel ? dgn : dgl;
    const ushort_t* Wb = WbLin + (size_t)rel * (12 * 4096);
    const float* bmp = bmpAll + (2 + rel) * H;
    const float* bu  = (rel ? bu_ln : bu_nl) + H;
    ushort_t* Out = rel ? outn : outl;

    __shared__ ushort_t A_lds[128 * LSTR];
    __shared__ ushort_t B_lds[128 * LSTR];

    int tid = threadIdx.x;
    int lane = tid & 63;
    int wave = tid >> 6;
    int wm = wave >> 1, wn = wave & 1;
    int m0 = blockIdx.x * 128;

    int arow = tid >> 3;     // 0..31
    int kq = tid & 7;        // k-chunk of 4 bf16
    float dpre[4];
    bool vrow[4];
#pragma unroll
    for (int p = 0; p < 4; ++p) {
        int grow = m0 + arow + 32 * p;
        vrow[p] = grow < M;
        dpre[p] = vrow[p] ? deg[grow] : 0.f;
    }
    int bc = tid >> 1;
    int bh = tid & 1;

    f32x4 acc[4][4];
#pragma unroll
    for (int i = 0; i < 4; ++i)
#pragma unroll
        for (int j = 0; j < 4; ++j)
            acc[i][j] = (f32x4){0.f, 0.f, 0.f, 0.f};

    int lrow = lane & 15, lg = lane >> 4;

    for (int kt = 0; kt < 12; ++kt) {
        int k0 = kt * 32;
        int piece = k0 >> 7;                  // 0:S 1:deg*X 2:X
        const ushort_t* Asrc = (piece == 0) ? S : X;
        int kin = (k0 & 127) + kq * 4;
        // ---- stage A ----
#pragma unroll
        for (int p = 0; p < 4; ++p) {
            int row = arow + 32 * p;
            uint2 w = make_uint2(0u, 0u);
            if (vrow[p]) w = *(const uint2*)(Asrc + (size_t)(m0 + row) * H + kin);
            if (piece == 1) {
                float d = dpre[p];
                float v0 = d * bf2f((ushort_t)(w.x & 0xFFFF));
                float v1 = d * bf2f((ushort_t)(w.x >> 16));
                float v2 = d * bf2f((ushort_t)(w.y & 0xFFFF));
                float v3 = d * bf2f((ushort_t)(w.y >> 16));
                w.x = (unsigned)f2bf(v0) | ((unsigned)f2bf(v1) << 16);
                w.y = (unsigned)f2bf(v2) | ((unsigned)f2bf(v3) << 16);
            }
            *(uint2*)&A_lds[row * LSTR + kq * 4] = w;
        }
        // ---- stage B ----
        {
            uint4 b0 = *(const uint4*)(Wb + (size_t)kt * 4096 + bc * 32 + bh * 16);
            *(uint4*)&B_lds[bc * LSTR + bh * 16] = b0;
            uint4 b1 = *(const uint4*)(Wb + (size_t)kt * 4096 + bc * 32 + bh * 16 + 8);
            *(uint4*)&B_lds[bc * LSTR + bh * 16 + 8] = b1;
        }
        __syncthreads();

        bf16x8 af[4], bfv[4];
#pragma unroll
        for (int mf = 0; mf < 4; ++mf)
            af[mf] = *(const bf16x8*)&A_lds[(wm * 64 + mf * 16 + lrow) * LSTR + lg * 8];
#pragma unroll
        for (int nf = 0; nf < 4; ++nf)
            bfv[nf] = *(const bf16x8*)&B_lds[(wn * 64 + nf * 16 + lrow) * LSTR + lg * 8];
#pragma unroll
        for (int mf = 0; mf < 4; ++mf)
#pragma unroll
            for (int nf = 0; nf < 4; ++nf)
                acc[mf][nf] = __builtin_amdgcn_mfma_f32_16x16x32_bf16(
                    af[mf], bfv[nf], acc[mf][nf], 0, 0, 0);
        __syncthreads();
    }

    float bmpv[4], buv[4];
#pragma unroll
    for (int nf = 0; nf < 4; ++nf) {
        int col = wn * 64 + nf * 16 + lrow;
        bmpv[nf] = bmp[col];
        buv[nf] = bu[col];
    }
#pragma unroll
    for (int mf = 0; mf < 4; ++mf) {
#pragma unroll
        for (int r = 0; r < 4; ++r) {
            int row = m0 + wm * 64 + mf * 16 + lg * 4 + r;
            if (row < M) {
                float d = deg[row];
#pragma unroll
                for (int nf = 0; nf < 4; ++nf) {
                    int col = wn * 64 + nf * 16 + lrow;
                    float v = acc[mf][nf][r] + d * bmpv[nf] + buv[nf];
                    Out[(size_t)row * H + col] = f2bf(fmaxf(v, 0.f));
                }
            }
        }
    }
}

// ---------------- global mean pool (bf16 input) ----------------
#define PR 256
__global__ void pool_sum(const ushort_t* __restrict__ xl, const int* __restrict__ batch,
                         float* __restrict__ sums) {
    int base = blockIdx.x * PR;
    int col = threadIdx.x & 127;
    int half = threadIdx.x >> 7;
    int rows = min(PR, NL - base);
    float acc = 0.f;
    int cur = -1;
    for (int r = half; r < rows; r += 2) {
        int row = base + r;
        int g = batch[row];
        if (g != cur) {
            if (cur >= 0) atomicAdd(&sums[cur * H + col], acc);
            acc = 0.f;
            cur = g;
        }
        acc += bf2f(xl[(size_t)row * H + col]);
    }
    if (cur >= 0) atomicAdd(&sums[cur * H + col], acc);
}

__global__ void pool_counts(const int* __restrict__ batch, float* __restrict__ cnt) {
    int g = threadIdx.x;
    if (g >= NG) return;
    int lo = 0, hi = NL;
    while (lo < hi) { int mid = (lo + hi) >> 1; if (batch[mid] < g) lo = mid + 1; else hi = mid; }
    int first = lo;
    lo = 0; hi = NL;
    while (lo < hi) { int mid = (lo + hi) >> 1; if (batch[mid] < g + 1) lo = mid + 1; else hi = mid; }
    cnt[g] = (float)(lo - first);
}

__global__ void pool_final(const float* __restrict__ sums, const float* __restrict__ cnt,
                           float* __restrict__ out) {
    int idx = blockIdx.x * blockDim.x + threadIdx.x;
    int g = idx / H;
    out[idx] = sums[idx] / fmaxf(cnt[g], 1.f);
}

static inline size_t rup(size_t n) { return (n + 15) & ~(size_t)15; }

extern "C" void kernel_launch(void* const* d_in, const int* in_sizes, int n_in,
                              void* d_out, int out_size, void* d_ws, size_t ws_size,
                              hipStream_t stream) {
    const float* x_node = (const float*)d_in[0];
    const float* x_link = (const float*)d_in[1];
    const float* Wm_nl  = (const float*)d_in[2];
    const float* bm_nl  = (const float*)d_in[3];
    const float* Wu_nl  = (const float*)d_in[4];
    const float* bu_nl  = (const float*)d_in[5];
    const float* Wm_ln  = (const float*)d_in[6];
    const float* bm_ln  = (const float*)d_in[7];
    const float* Wu_ln  = (const float*)d_in[8];
    const float* bu_ln  = (const float*)d_in[9];
    const int* nl_edge  = (const int*)d_in[10];
    const int* ln_edge  = (const int*)d_in[11];
    const int* batch_link = (const int*)d_in[12];
    (void)in_sizes; (void)n_in; (void)out_size; (void)ws_size;

    char* wsb = (char*)d_ws;
    size_t o = 0;
    auto alloc = [&](size_t elems) { void* p = wsb + o * 4; o += rup(elems); return p; };
    ushort_t* xnb  = (ushort_t*)alloc((size_t)NN * H / 2);   // bf16 hidden state
    ushort_t* xlb  = (ushort_t*)alloc((size_t)NL * H / 2);
    ushort_t* Sbl  = (ushort_t*)alloc((size_t)NL * H / 2);   // bf16 gathered sums
    ushort_t* Sbn  = (ushort_t*)alloc((size_t)NN * H / 2);
    float* S8l   = (float*)alloc((size_t)NL * FR);
    float* S8n   = (float*)alloc((size_t)NN * FR);
    float* deg_l = (float*)alloc(NL);
    float* deg_n = (float*)alloc(NN);
    int*   idl   = (int*)alloc(NL);
    int*   idn   = (int*)alloc(NN);
    int*   offL  = (int*)alloc(NL + 1);
    int*   offN  = (int*)alloc(NN + 1);
    int*   curL  = (int*)alloc(NL);
    int*   curN  = (int*)alloc(NN);
    int*   adjL  = (int*)alloc(NE);
    int*   adjN  = (int*)alloc(NE);
    float* Wstack= (float*)alloc(4L * 384 * H);
    float* bmp   = (float*)alloc(4 * H);
    float* sums  = (float*)alloc(NG * H);
    float* cnt   = (float*)alloc(NG);
    int*   bsum  = (int*)alloc(2 * SNB);
    int*   bbase = (int*)alloc(2 * SNB);
    ushort_t* WbLin = (ushort_t*)alloc(2 * 12 * 4096 / 2);

    hipMemsetAsync(idl, 0, (size_t)(rup(NL) + NN) * sizeof(int), stream);
    hipMemsetAsync(sums, 0, (size_t)NG * H * sizeof(float), stream);

    precompute_w<<<(4 * (384 * H + H) + 255) / 256, 256, 0, stream>>>(
        Wm_nl, bm_nl, Wu_nl, Wm_ln, bm_ln, Wu_ln, Wstack, bmp, WbLin);
    compute_deg<<<(NE + 255) / 256, 256, 0, stream>>>(nl_edge, ln_edge, idl, idn);
    scan1<<<2 * SNB, 256, 0, stream>>>(idl, idn, bsum);
    scan2<<<1, 128, 0, stream>>>(bsum, bbase);
    scan3<<<2 * SNB, 256, 0, stream>>>(idl, idn, bbase, offL, offN, curL, curN, deg_l, deg_n);
    fill_csr<<<(NE + 255) / 256, 256, 0, stream>>>(nl_edge, ln_edge, curL, curN, adjL, adjN);
    pool_counts<<<1, 64, 0, stream>>>(batch_link, cnt);

    // ---- layer 1 ----
    gather_sum8_2<<<dim3((NL * FR + 255) / 256, 2), 256, 0, stream>>>(
        offL, adjL, x_node, S8l, offN, adjN, x_link, S8n);
    gemm_l1<<<dim3((NL + 7) / 8, 2), 256, 0, stream>>>(
        S8l, x_link, deg_l, S8n, x_node, deg_n, Wstack, bmp, bu_nl, bu_ln, xlb, xnb);

    // ---- layer 2 ----
    gather_bf<<<dim3((NL + 7) / 8, 2), 256, 0, stream>>>(
        offL, adjL, xnb, Sbl, offN, adjN, xlb, Sbn);
    gemm_mfma<<<dim3((NL + 127) / 128, 2), 256, 0, stream>>>(
        Sbl, xlb, deg_l, Sbn, xnb, deg_n, WbLin, bmp, bu_nl, bu_ln, xlb, xnb, NL);

    pool_sum<<<(NL + PR - 1) / PR, 256, 0, stream>>>(xlb, batch_link, sums);
    pool_final<<<(NG * H) / 256, 256, 0, stream>>>(sums, cnt, (float*)d_out);
}

// Round 9
// 232.839 us; speedup vs baseline: 1.9490x; 1.2292x over previous
//
#include <hip/hip_runtime.h>

// HeteroGNN fused implementation, round 9.
// Algebra: new = relu( S @ W1 + deg.*(x @ W2) + x @ W3 + deg.*bmp + bu )
// Round-9: (a) CSR build restructured as 3-pass bucketed build (49 buckets of
// 1024 dsts) -- kills fill_csr's 16x scattered-write amplification (53MB->~4MB)
// and compute_deg's 800k global atomics; (b) layer-2 MFMA GEMM tile 128x128 ->
// 64x128 (grid 782->1564, 3->6 blocks/CU; was grid-limited at 20% occupancy).

#define H 128
#define NN 50000
#define NL 50000
#define NE 400000
#define NG 64
#define FR 8
#define SNB 49
#define NB 49          // dst buckets (dst >> 10)
#define BCAP 12288     // entries per bucket (expected 8192, sigma ~90)

typedef __attribute__((ext_vector_type(8))) short bf16x8;
typedef __attribute__((ext_vector_type(4))) float f32x4;
typedef unsigned short ushort_t;
typedef unsigned int uint_t;

__device__ __forceinline__ ushort_t f2bf(float f) {
    union { float f; unsigned u; } v; v.f = f;
    unsigned r = v.u + 0x7FFFu + ((v.u >> 16) & 1u);   // RNE
    return (ushort_t)(r >> 16);
}
__device__ __forceinline__ float bf2f(ushort_t u) {
    union { unsigned u; float f; } v; v.u = ((unsigned)u) << 16; return v.f;
}

// ---------------- weight fusion (+ bf16 per-tile layout for layer-2) ----------------
__global__ void precompute_w(const float* __restrict__ Wm_nl, const float* __restrict__ bm_nl,
                             const float* __restrict__ Wu_nl,
                             const float* __restrict__ Wm_ln, const float* __restrict__ bm_ln,
                             const float* __restrict__ Wu_ln,
                             float* __restrict__ Wstack, float* __restrict__ bmp,
                             ushort_t* __restrict__ WbLin) {
    int idx = blockIdx.x * blockDim.x + threadIdx.x;
    const int per = 384 * H + H;
    int c = idx / per, r = idx % per;
    if (c >= 4) return;
    int l = c >> 1, rel = c & 1;
    const float* Wm = (rel ? Wm_ln : Wm_nl) + l * 256 * H;
    const float* Wu = (rel ? Wu_ln : Wu_nl) + l * 256 * H;
    const float* bm = (rel ? bm_ln : bm_nl) + l * H;
    float* Ws = Wstack + c * 384 * H;
    if (r < 384 * H) {
        int t = r / H, j = r % H;
        float val;
        if (t < 256) {
            float acc = 0.f;
            for (int k = 0; k < H; ++k) acc += Wm[t * H + k] * Wu[k * H + j];
            val = acc;
        } else {
            val = Wu[(t - 128) * H + j];
        }
        Ws[t * H + j] = val;
        if (c >= 2) {
            WbLin[(size_t)(c - 2) * (12 * 4096) + (size_t)(t >> 5) * 4096 + j * 32 + (t & 31)]
                = f2bf(val);
        }
    } else {
        int j = r - 384 * H;
        float acc = 0.f;
        for (int k = 0; k < H; ++k) acc += bm[k] * Wu[k * H + j];
        bmp[c * H + j] = acc;
    }
}

// ---------------- pass A: bucket-scatter edges by dst ----------------
// entry = src | (dstlo << 16)  (src < 65536, dstlo < 1024)
__launch_bounds__(256)
__global__ void bucket_scatter(const int* __restrict__ nl, const int* __restrict__ ln,
                               uint_t* __restrict__ bbuf, int* __restrict__ gcount) {
    int rel = blockIdx.y;
    const int* edge = rel ? ln : nl;
    uint_t* bb = bbuf + (size_t)rel * NB * BCAP;
    int* gc = gcount + rel * NB;
    __shared__ int hist[NB], base[NB], cur[NB];
    int tid = threadIdx.x;
    if (tid < NB) hist[tid] = 0;
    __syncthreads();
    int e0 = blockIdx.x * 2048 + tid;
    int src[8], dst[8];
#pragma unroll
    for (int i = 0; i < 8; ++i) {
        int e = e0 + i * 256;
        if (e < NE) {
            src[i] = edge[e];
            dst[i] = edge[NE + e];
            atomicAdd(&hist[dst[i] >> 10], 1);
        } else dst[i] = -1;
    }
    __syncthreads();
    if (tid < NB) { base[tid] = atomicAdd(&gc[tid], hist[tid]); cur[tid] = 0; }
    __syncthreads();
#pragma unroll
    for (int i = 0; i < 8; ++i) {
        if (dst[i] >= 0) {
            int b = dst[i] >> 10;
            int p = base[b] + atomicAdd(&cur[b], 1);
            bb[(size_t)b * BCAP + p] = (uint_t)src[i] | ((uint_t)(dst[i] & 1023) << 16);
        }
    }
}

// ---------------- pass B: per-bucket degree via LDS histogram ----------------
__launch_bounds__(256)
__global__ void bucket_deg(const uint_t* __restrict__ bbuf, const int* __restrict__ gcount,
                           int* __restrict__ degL, int* __restrict__ degN) {
    int rel = blockIdx.y, b = blockIdx.x;
    const uint_t* bb = bbuf + ((size_t)rel * NB + b) * BCAP;
    int n = gcount[rel * NB + b];
    int* deg = rel ? degN : degL;
    __shared__ int ld[1024];
    int tid = threadIdx.x;
    for (int i = tid; i < 1024; i += 256) ld[i] = 0;
    __syncthreads();
    for (int i = tid; i < n; i += 256) atomicAdd(&ld[bbuf ? (bb[i] >> 16) : 0], 1);
    __syncthreads();
    int dbase = b << 10;
    for (int i = tid; i < 1024; i += 256) {
        int d = dbase + i;
        if (d < NL) deg[d] = ld[i];
    }
}

// ---------------- 3-phase parallel scan over degrees ----------------
__global__ void scan1(const int* __restrict__ degL, const int* __restrict__ degN,
                      int* __restrict__ bsum) {
    int arr = blockIdx.x / SNB, blk = blockIdx.x % SNB;
    const int* deg = arr ? degN : degL;
    int tid = threadIdx.x;
    int base = blk * 1024 + tid * 4;
    int s = 0;
#pragma unroll
    for (int i = 0; i < 4; ++i) { int idx = base + i; if (idx < NL) s += deg[idx]; }
    __shared__ int red[256];
    red[tid] = s;
    __syncthreads();
    for (int d = 128; d > 0; d >>= 1) {
        if (tid < d) red[tid] += red[tid + d];
        __syncthreads();
    }
    if (tid == 0) bsum[blockIdx.x] = red[0];
}

__global__ void scan2(const int* __restrict__ bsum, int* __restrict__ bbase) {
    __shared__ int sh[128];
    int tid = threadIdx.x;
    int v0 = (tid < 2 * SNB) ? bsum[tid] : 0;
    sh[tid] = v0;
    __syncthreads();
    int gstart = (tid < SNB) ? 0 : SNB;
    for (int d = 1; d < 64; d <<= 1) {
        int v = (tid >= gstart + d && tid < 2 * SNB) ? sh[tid - d] : 0;
        __syncthreads();
        sh[tid] += v;
        __syncthreads();
    }
    if (tid < 2 * SNB) bbase[tid] = sh[tid] - v0;
}

__global__ void scan3(const int* __restrict__ degL, const int* __restrict__ degN,
                      const int* __restrict__ bbase,
                      int* __restrict__ offL, int* __restrict__ offN,
                      float* __restrict__ fdegL, float* __restrict__ fdegN) {
    int arr = blockIdx.x / SNB, blk = blockIdx.x % SNB;
    const int* deg = arr ? degN : degL;
    int* off = arr ? offN : offL;
    float* fdeg = arr ? fdegN : fdegL;
    int tid = threadIdx.x;
    int base = blk * 1024 + tid * 4;
    int d4[4]; int s = 0;
#pragma unroll
    for (int i = 0; i < 4; ++i) {
        int idx = base + i;
        d4[i] = (idx < NL) ? deg[idx] : 0;
        s += d4[i];
    }
    __shared__ int part[256];
    part[tid] = s;
    __syncthreads();
    for (int d = 1; d < 256; d <<= 1) {
        int v = (tid >= d) ? part[tid - d] : 0;
        __syncthreads();
        part[tid] += v;
        __syncthreads();
    }
    int run = bbase[blockIdx.x] + part[tid] - s;
#pragma unroll
    for (int i = 0; i < 4; ++i) {
        int idx = base + i;
        if (idx < NL) {
            off[idx] = run; fdeg[idx] = (float)d4[i];
            run += d4[i];
            if (idx == NL - 1) off[NL] = run;
        }
    }
}

// ---------------- pass C: per-bucket CSR fill (LDS cursors, L2-local writes) ----------------
__launch_bounds__(256)
__global__ void bucket_fill(const uint_t* __restrict__ bbuf, const int* __restrict__ gcount,
                            const int* __restrict__ offL, const int* __restrict__ offN,
                            int* __restrict__ adjL, int* __restrict__ adjN) {
    int rel = blockIdx.y, b = blockIdx.x;
    const uint_t* bb = bbuf + ((size_t)rel * NB + b) * BCAP;
    int n = gcount[rel * NB + b];
    const int* off = rel ? offN : offL;
    int* adj = rel ? adjN : adjL;
    __shared__ int lcur[1024];
    int tid = threadIdx.x;
    int dbase = b << 10;
    for (int i = tid; i < 1024; i += 256) {
        int d = dbase + i;
        lcur[i] = (d < NL) ? off[d] : 0;
    }
    __syncthreads();
    for (int i = tid; i < n; i += 256) {
        uint_t v = bb[i];
        int p = atomicAdd(&lcur[v >> 16], 1);
        adj[p] = (int)(v & 0xFFFFu);
    }
}

// ---------------- layer-1 gather (raw 8-col), both relations ----------------
__launch_bounds__(256)
__global__ void gather_sum8_2(const int* __restrict__ offL, const int* __restrict__ adjL,
                              const float* __restrict__ xnode, float* __restrict__ S8l,
                              const int* __restrict__ offN, const int* __restrict__ adjN,
                              const float* __restrict__ xlink, float* __restrict__ S8n) {
    int rel = blockIdx.y;
    const int* off = rel ? offN : offL;
    const int* adj = rel ? adjN : adjL;
    const float* Xr = rel ? xlink : xnode;
    float* S8 = rel ? S8n : S8l;
    int t = blockIdx.x * 256 + threadIdx.x;
    int row = t >> 3, c = t & 7;
    if (row >= NL) return;
    int beg = off[row], end = off[row + 1];
    float acc = 0.f;
    for (int i = beg; i < end; ++i)
        acc += Xr[(size_t)adj[i] * FR + c];
    S8[row * FR + c] = acc;
}

// ---------------- layer-1 fused GEMM, direct per-row (K=24) ----------------
__launch_bounds__(256)
__global__ void gemm_l1(const float* __restrict__ S8l, const float* __restrict__ xlink,
                        const float* __restrict__ dgl,
                        const float* __restrict__ S8n, const float* __restrict__ xnode,
                        const float* __restrict__ dgn,
                        const float* __restrict__ Wstack, const float* __restrict__ bmpAll,
                        const float* __restrict__ bu_nl, const float* __restrict__ bu_ln,
                        ushort_t* __restrict__ outl, ushort_t* __restrict__ outn) {
    int rel = blockIdx.y;
    const float* S8  = rel ? S8n : S8l;
    const float* Xr  = rel ? xnode : xlink;
    const float* deg = rel ? dgn : dgl;
    const float* Ws  = Wstack + (size_t)rel * 384 * H;
    const float* bmp = bmpAll + rel * H;
    const float* bu  = rel ? bu_ln : bu_nl;
    ushort_t* Out = rel ? outn : outl;

    __shared__ float Wl[24][H];
    __shared__ float bf2[2][H];
    int tid = threadIdx.x;
    for (int p = tid; p < 24 * H; p += 256) {
        int kk = p >> 7, c = p & 127;
        int srcrow = (kk >> 3) * 128 + (kk & 7);
        Wl[kk][c] = Ws[srcrow * H + c];
    }
    if (tid < 128) { bf2[0][tid] = bmp[tid]; bf2[1][tid] = bu[tid]; }
    __syncthreads();

    int rl = tid >> 5;
    int cg = tid & 31;
    int row = blockIdx.x * 8 + rl;
    if (row >= NL) return;
    float d = deg[row];
    float a[16];
    *(float4*)(a)      = *(const float4*)(S8 + (size_t)row * FR);
    *(float4*)(a + 4)  = *(const float4*)(S8 + (size_t)row * FR + 4);
    *(float4*)(a + 8)  = *(const float4*)(Xr + (size_t)row * FR);
    *(float4*)(a + 12) = *(const float4*)(Xr + (size_t)row * FR + 4);

    int c0 = cg * 4;
    float acc[4] = {0.f, 0.f, 0.f, 0.f};
#pragma unroll
    for (int k = 0; k < 8; ++k) {
        float4 w = *(const float4*)(&Wl[k][c0]);
        float av = a[k];
        acc[0] += av * w.x; acc[1] += av * w.y; acc[2] += av * w.z; acc[3] += av * w.w;
    }
#pragma unroll
    for (int k = 0; k < 8; ++k) {
        float4 w = *(const float4*)(&Wl[8 + k][c0]);
        float av = d * a[8 + k];
        acc[0] += av * w.x; acc[1] += av * w.y; acc[2] += av * w.z; acc[3] += av * w.w;
    }
#pragma unroll
    for (int k = 0; k < 8; ++k) {
        float4 w = *(const float4*)(&Wl[16 + k][c0]);
        float av = a[8 + k];
        acc[0] += av * w.x; acc[1] += av * w.y; acc[2] += av * w.z; acc[3] += av * w.w;
    }
    uint2 o;
    {
        float v0 = fmaxf(acc[0] + d * bf2[0][c0 + 0] + bf2[1][c0 + 0], 0.f);
        float v1 = fmaxf(acc[1] + d * bf2[0][c0 + 1] + bf2[1][c0 + 1], 0.f);
        float v2 = fmaxf(acc[2] + d * bf2[0][c0 + 2] + bf2[1][c0 + 2], 0.f);
        float v3 = fmaxf(acc[3] + d * bf2[0][c0 + 3] + bf2[1][c0 + 3], 0.f);
        o.x = (unsigned)f2bf(v0) | ((unsigned)f2bf(v1) << 16);
        o.y = (unsigned)f2bf(v2) | ((unsigned)f2bf(v3) << 16);
    }
    *(uint2*)(Out + (size_t)row * H + c0) = o;
}

// ---------------- layer-2 gather (bf16 in, fp32 accum, bf16 out) ----------------
__launch_bounds__(256)
__global__ void gather_bf(const int* __restrict__ offL, const int* __restrict__ adjL,
                          const ushort_t* __restrict__ xnb, ushort_t* __restrict__ Sbl,
                          const int* __restrict__ offN, const int* __restrict__ adjN,
                          const ushort_t* __restrict__ xlb, ushort_t* __restrict__ Sbn) {
    int rel = blockIdx.y;
    const int* off = rel ? offN : offL;
    const int* adj = rel ? adjN : adjL;
    const ushort_t* X = rel ? xlb : xnb;
    ushort_t* Sg = rel ? Sbn : Sbl;
    int row = blockIdx.x * 8 + (threadIdx.x >> 5);
    int lane = threadIdx.x & 31;
    if (row >= NL) return;
    int beg = off[row], end = off[row + 1];
    float a0 = 0.f, a1 = 0.f, a2 = 0.f, a3 = 0.f;
    float b0 = 0.f, b1 = 0.f, b2 = 0.f, b3 = 0.f;
    int i = beg;
    for (; i + 1 < end; i += 2) {
        uint2 ua = *(const uint2*)(X + (size_t)adj[i] * H + lane * 4);
        uint2 ub = *(const uint2*)(X + (size_t)adj[i + 1] * H + lane * 4);
        a0 += bf2f((ushort_t)(ua.x & 0xFFFF)); a1 += bf2f((ushort_t)(ua.x >> 16));
        a2 += bf2f((ushort_t)(ua.y & 0xFFFF)); a3 += bf2f((ushort_t)(ua.y >> 16));
        b0 += bf2f((ushort_t)(ub.x & 0xFFFF)); b1 += bf2f((ushort_t)(ub.x >> 16));
        b2 += bf2f((ushort_t)(ub.y & 0xFFFF)); b3 += bf2f((ushort_t)(ub.y >> 16));
    }
    if (i < end) {
        uint2 ua = *(const uint2*)(X + (size_t)adj[i] * H + lane * 4);
        a0 += bf2f((ushort_t)(ua.x & 0xFFFF)); a1 += bf2f((ushort_t)(ua.x >> 16));
        a2 += bf2f((ushort_t)(ua.y & 0xFFFF)); a3 += bf2f((ushort_t)(ua.y >> 16));
    }
    uint2 o;
    o.x = (unsigned)f2bf(a0 + b0) | ((unsigned)f2bf(a1 + b1) << 16);
    o.y = (unsigned)f2bf(a2 + b2) | ((unsigned)f2bf(a3 + b3) << 16);
    *(uint2*)(Sg + (size_t)row * H + lane * 4) = o;
}

// ---------------- layer-2 fused GEMM via MFMA bf16: 64x128 tile ----------------
#define LSTR 40
__launch_bounds__(256)
__global__ void gemm_mfma(const ushort_t* __restrict__ Sbl, const ushort_t* __restrict__ xlb,
                          const float* __restrict__ dgl,
                          const ushort_t* __restrict__ Sbn, const ushort_t* __restrict__ xnb,
                          const float* __restrict__ dgn,
                          const ushort_t* __restrict__ WbLin, const float* __restrict__ bmpAll,
                          const float* __restrict__ bu_nl, const float* __restrict__ bu_ln,
                          ushort_t* __restrict__ outl, ushort_t* __restrict__ outn, int M) {
    int rel = blockIdx.y;
    const ushort_t* S  = rel ? Sbn : Sbl;
    const ushort_t* X  = rel ? xnb : xlb;
    const float* deg = rel ? dgn : dgl;
    const ushort_t* Wb = WbLin + (size_t)rel * (12 * 4096);
    const float* bmp = bmpAll + (2 + rel) * H;
    const float* bu  = (rel ? bu_ln : bu_nl) + H;
    ushort_t* Out = rel ? outn : outl;

    __shared__ ushort_t A_lds[64 * LSTR];    // 5.1 KB
    __shared__ ushort_t B_lds[128 * LSTR];   // 10.2 KB

    int tid = threadIdx.x;
    int lane = tid & 63;
    int wave = tid >> 6;          // wave = col group (32 cols each)
    int m0 = blockIdx.x * 64;

    // A staging: thread -> (row = tid>>2, k-chunk kc = tid&3 of 8 bf16)
    int arow = tid >> 2, kc = tid & 3;
    int grow = m0 + arow;
    bool vr = grow < M;
    float dr = vr ? deg[grow] : 0.f;
    // B staging: thread -> (col bc = tid>>1, half bh = tid&1), 2x uint4
    int bc = tid >> 1, bh = tid & 1;

    f32x4 acc[4][2];
#pragma unroll
    for (int i = 0; i < 4; ++i)
#pragma unroll
        for (int j = 0; j < 2; ++j)
            acc[i][j] = (f32x4){0.f, 0.f, 0.f, 0.f};

    int lrow = lane & 15, lg = lane >> 4;

    for (int kt = 0; kt < 12; ++kt) {
        int k0 = kt * 32;
        int piece = k0 >> 7;                  // 0:S 1:deg*X 2:X
        const ushort_t* Asrc = (piece == 0) ? S : X;
        int kin = (k0 & 127) + kc * 8;
        // ---- stage A (uint4 = 8 bf16) ----
        uint4 w = make_uint4(0u, 0u, 0u, 0u);
        if (vr) w = *(const uint4*)(Asrc + (size_t)grow * H + kin);
        if (piece == 1) {
            unsigned* wp = (unsigned*)&w;
#pragma unroll
            for (int q = 0; q < 4; ++q) {
                float v0 = dr * bf2f((ushort_t)(wp[q] & 0xFFFF));
                float v1 = dr * bf2f((ushort_t)(wp[q] >> 16));
                wp[q] = (unsigned)f2bf(v0) | ((unsigned)f2bf(v1) << 16);
            }
        }
        *(uint4*)&A_lds[arow * LSTR + kc * 8] = w;
        // ---- stage B ----
        {
            uint4 b0 = *(const uint4*)(Wb + (size_t)kt * 4096 + bc * 32 + bh * 16);
            *(uint4*)&B_lds[bc * LSTR + bh * 16] = b0;
            uint4 b1 = *(const uint4*)(Wb + (size_t)kt * 4096 + bc * 32 + bh * 16 + 8);
            *(uint4*)&B_lds[bc * LSTR + bh * 16 + 8] = b1;
        }
        __syncthreads();

        bf16x8 af[4], bfv[2];
#pragma unroll
        for (int mf = 0; mf < 4; ++mf)
            af[mf] = *(const bf16x8*)&A_lds[(mf * 16 + lrow) * LSTR + lg * 8];
#pragma unroll
        for (int nf = 0; nf < 2; ++nf)
            bfv[nf] = *(const bf16x8*)&B_lds[(wave * 32 + nf * 16 + lrow) * LSTR + lg * 8];
#pragma unroll
        for (int mf = 0; mf < 4; ++mf)
#pragma unroll
            for (int nf = 0; nf < 2; ++nf)
                acc[mf][nf] = __builtin_amdgcn_mfma_f32_16x16x32_bf16(
                    af[mf], bfv[nf], acc[mf][nf], 0, 0, 0);
        __syncthreads();
    }

    float bmpv[2], buv[2];
#pragma unroll
    for (int nf = 0; nf < 2; ++nf) {
        int col = wave * 32 + nf * 16 + lrow;
        bmpv[nf] = bmp[col];
        buv[nf] = bu[col];
    }
#pragma unroll
    for (int mf = 0; mf < 4; ++mf) {
#pragma unroll
        for (int r = 0; r < 4; ++r) {
            int row = m0 + mf * 16 + lg * 4 + r;
            if (row < M) {
                float d = deg[row];
#pragma unroll
                for (int nf = 0; nf < 2; ++nf) {
                    int col = wave * 32 + nf * 16 + lrow;
                    float v = acc[mf][nf][r] + d * bmpv[nf] + buv[nf];
                    Out[(size_t)row * H + col] = f2bf(fmaxf(v, 0.f));
                }
            }
        }
    }
}

// ---------------- global mean pool (bf16 input) ----------------
#define PR 256
__global__ void pool_sum(const ushort_t* __restrict__ xl, const int* __restrict__ batch,
                         float* __restrict__ sums) {
    int base = blockIdx.x * PR;
    int col = threadIdx.x & 127;
    int half = threadIdx.x >> 7;
    int rows = min(PR, NL - base);
    float acc = 0.f;
    int cur = -1;
    for (int r = half; r < rows; r += 2) {
        int row = base + r;
        int g = batch[row];
        if (g != cur) {
            if (cur >= 0) atomicAdd(&sums[cur * H + col], acc);
            acc = 0.f;
            cur = g;
        }
        acc += bf2f(xl[(size_t)row * H + col]);
    }
    if (cur >= 0) atomicAdd(&sums[cur * H + col], acc);
}

__global__ void pool_counts(const int* __restrict__ batch, float* __restrict__ cnt) {
    int g = threadIdx.x;
    if (g >= NG) return;
    int lo = 0, hi = NL;
    while (lo < hi) { int mid = (lo + hi) >> 1; if (batch[mid] < g) lo = mid + 1; else hi = mid; }
    int first = lo;
    lo = 0; hi = NL;
    while (lo < hi) { int mid = (lo + hi) >> 1; if (batch[mid] < g + 1) lo = mid + 1; else hi = mid; }
    cnt[g] = (float)(lo - first);
}

__global__ void pool_final(const float* __restrict__ sums, const float* __restrict__ cnt,
                           float* __restrict__ out) {
    int idx = blockIdx.x * blockDim.x + threadIdx.x;
    int g = idx / H;
    out[idx] = sums[idx] / fmaxf(cnt[g], 1.f);
}

static inline size_t rup(size_t n) { return (n + 15) & ~(size_t)15; }

extern "C" void kernel_launch(void* const* d_in, const int* in_sizes, int n_in,
                              void* d_out, int out_size, void* d_ws, size_t ws_size,
                              hipStream_t stream) {
    const float* x_node = (const float*)d_in[0];
    const float* x_link = (const float*)d_in[1];
    const float* Wm_nl  = (const float*)d_in[2];
    const float* bm_nl  = (const float*)d_in[3];
    const float* Wu_nl  = (const float*)d_in[4];
    const float* bu_nl  = (const float*)d_in[5];
    const float* Wm_ln  = (const float*)d_in[6];
    const float* bm_ln  = (const float*)d_in[7];
    const float* Wu_ln  = (const float*)d_in[8];
    const float* bu_ln  = (const float*)d_in[9];
    const int* nl_edge  = (const int*)d_in[10];
    const int* ln_edge  = (const int*)d_in[11];
    const int* batch_link = (const int*)d_in[12];
    (void)in_sizes; (void)n_in; (void)out_size; (void)ws_size;

    char* wsb = (char*)d_ws;
    size_t o = 0;
    auto alloc = [&](size_t elems) { void* p = wsb + o * 4; o += rup(elems); return p; };
    ushort_t* xnb  = (ushort_t*)alloc((size_t)NN * H / 2);
    ushort_t* xlb  = (ushort_t*)alloc((size_t)NL * H / 2);
    ushort_t* Sbl  = (ushort_t*)alloc((size_t)NL * H / 2);
    ushort_t* Sbn  = (ushort_t*)alloc((size_t)NN * H / 2);
    float* S8l   = (float*)alloc((size_t)NL * FR);
    float* S8n   = (float*)alloc((size_t)NN * FR);
    float* deg_l = (float*)alloc(NL);
    float* deg_n = (float*)alloc(NN);
    int*   idl   = (int*)alloc(NL);
    int*   idn   = (int*)alloc(NN);
    int*   offL  = (int*)alloc(NL + 1);
    int*   offN  = (int*)alloc(NN + 1);
    int*   adjL  = (int*)alloc(NE);
    int*   adjN  = (int*)alloc(NE);
    float* Wstack= (float*)alloc(4L * 384 * H);
    float* bmp   = (float*)alloc(4 * H);
    float* sums  = (float*)alloc(NG * H);
    float* cnt   = (float*)alloc(NG);
    int*   bsum  = (int*)alloc(2 * SNB);
    int*   bbase = (int*)alloc(2 * SNB);
    ushort_t* WbLin = (ushort_t*)alloc(2 * 12 * 4096 / 2);
    uint_t* bbuf  = (uint_t*)alloc((size_t)2 * NB * BCAP);
    int*    gcount= (int*)alloc(2 * NB);

    hipMemsetAsync(gcount, 0, (size_t)2 * NB * sizeof(int), stream);
    hipMemsetAsync(sums, 0, (size_t)NG * H * sizeof(float), stream);

    precompute_w<<<(4 * (384 * H + H) + 255) / 256, 256, 0, stream>>>(
        Wm_nl, bm_nl, Wu_nl, Wm_ln, bm_ln, Wu_ln, Wstack, bmp, WbLin);

    // ---- CSR build (bucketed) ----
    bucket_scatter<<<dim3((NE + 2047) / 2048, 2), 256, 0, stream>>>(
        nl_edge, ln_edge, bbuf, gcount);
    bucket_deg<<<dim3(NB, 2), 256, 0, stream>>>(bbuf, gcount, idl, idn);
    scan1<<<2 * SNB, 256, 0, stream>>>(idl, idn, bsum);
    scan2<<<1, 128, 0, stream>>>(bsum, bbase);
    scan3<<<2 * SNB, 256, 0, stream>>>(idl, idn, bbase, offL, offN, deg_l, deg_n);
    bucket_fill<<<dim3(NB, 2), 256, 0, stream>>>(bbuf, gcount, offL, offN, adjL, adjN);
    pool_counts<<<1, 64, 0, stream>>>(batch_link, cnt);

    // ---- layer 1 ----
    gather_sum8_2<<<dim3((NL * FR + 255) / 256, 2), 256, 0, stream>>>(
        offL, adjL, x_node, S8l, offN, adjN, x_link, S8n);
    gemm_l1<<<dim3((NL + 7) / 8, 2), 256, 0, stream>>>(
        S8l, x_link, deg_l, S8n, x_node, deg_n, Wstack, bmp, bu_nl, bu_ln, xlb, xnb);

    // ---- layer 2 ----
    gather_bf<<<dim3((NL + 7) / 8, 2), 256, 0, stream>>>(
        offL, adjL, xnb, Sbl, offN, adjN, xlb, Sbn);
    gemm_mfma<<<dim3((NL + 63) / 64, 2), 256, 0, stream>>>(
        Sbl, xlb, deg_l, Sbn, xnb, deg_n, WbLin, bmp, bu_nl, bu_ln, xlb, xnb, NL);

    pool_sum<<<(NL + PR - 1) / PR, 256, 0, stream>>>(xlb, batch_link, sums);
    pool_final<<<(NG * H) / 256, 256, 0, stream>>>(sums, cnt, (float*)d_out);
}

// Round 10
// 195.980 us; speedup vs baseline: 2.3155x; 1.1881x over previous
//
#include <hip/hip_runtime.h>

// HeteroGNN fused implementation, round 10.
// Algebra: new = relu( S @ W1 + deg.*(x @ W2) + x @ W3 + deg.*bmp + bu )
// Round-10: pool_sum rewritten (was 43us: 196 blocks, scalar 2B loads, 7% occ
// -> 782 blocks, uint2 loads, LDS-reduced fast path for single-group blocks);
// pool_counts folded into pool_final.

#define H 128
#define NN 50000
#define NL 50000
#define NE 400000
#define NG 64
#define FR 8
#define SNB 49
#define NB 49          // dst buckets (dst >> 10)
#define BCAP 12288     // entries per bucket (expected 8192)

typedef __attribute__((ext_vector_type(8))) short bf16x8;
typedef __attribute__((ext_vector_type(4))) float f32x4;
typedef unsigned short ushort_t;
typedef unsigned int uint_t;

__device__ __forceinline__ ushort_t f2bf(float f) {
    union { float f; unsigned u; } v; v.f = f;
    unsigned r = v.u + 0x7FFFu + ((v.u >> 16) & 1u);   // RNE
    return (ushort_t)(r >> 16);
}
__device__ __forceinline__ float bf2f(ushort_t u) {
    union { unsigned u; float f; } v; v.u = ((unsigned)u) << 16; return v.f;
}

// ---------------- weight fusion (+ bf16 per-tile layout for layer-2) ----------------
__global__ void precompute_w(const float* __restrict__ Wm_nl, const float* __restrict__ bm_nl,
                             const float* __restrict__ Wu_nl,
                             const float* __restrict__ Wm_ln, const float* __restrict__ bm_ln,
                             const float* __restrict__ Wu_ln,
                             float* __restrict__ Wstack, float* __restrict__ bmp,
                             ushort_t* __restrict__ WbLin) {
    int idx = blockIdx.x * blockDim.x + threadIdx.x;
    const int per = 384 * H + H;
    int c = idx / per, r = idx % per;
    if (c >= 4) return;
    int l = c >> 1, rel = c & 1;
    const float* Wm = (rel ? Wm_ln : Wm_nl) + l * 256 * H;
    const float* Wu = (rel ? Wu_ln : Wu_nl) + l * 256 * H;
    const float* bm = (rel ? bm_ln : bm_nl) + l * H;
    float* Ws = Wstack + c * 384 * H;
    if (r < 384 * H) {
        int t = r / H, j = r % H;
        float val;
        if (t < 256) {
            float acc = 0.f;
            for (int k = 0; k < H; ++k) acc += Wm[t * H + k] * Wu[k * H + j];
            val = acc;
        } else {
            val = Wu[(t - 128) * H + j];
        }
        Ws[t * H + j] = val;
        if (c >= 2) {
            WbLin[(size_t)(c - 2) * (12 * 4096) + (size_t)(t >> 5) * 4096 + j * 32 + (t & 31)]
                = f2bf(val);
        }
    } else {
        int j = r - 384 * H;
        float acc = 0.f;
        for (int k = 0; k < H; ++k) acc += bm[k] * Wu[k * H + j];
        bmp[c * H + j] = acc;
    }
}

// ---------------- pass A: bucket-scatter edges by dst ----------------
__launch_bounds__(256)
__global__ void bucket_scatter(const int* __restrict__ nl, const int* __restrict__ ln,
                               uint_t* __restrict__ bbuf, int* __restrict__ gcount) {
    int rel = blockIdx.y;
    const int* edge = rel ? ln : nl;
    uint_t* bb = bbuf + (size_t)rel * NB * BCAP;
    int* gc = gcount + rel * NB;
    __shared__ int hist[NB], base[NB], cur[NB];
    int tid = threadIdx.x;
    if (tid < NB) hist[tid] = 0;
    __syncthreads();
    int e0 = blockIdx.x * 2048 + tid;
    int src[8], dst[8];
#pragma unroll
    for (int i = 0; i < 8; ++i) {
        int e = e0 + i * 256;
        if (e < NE) {
            src[i] = edge[e];
            dst[i] = edge[NE + e];
            atomicAdd(&hist[dst[i] >> 10], 1);
        } else dst[i] = -1;
    }
    __syncthreads();
    if (tid < NB) { base[tid] = atomicAdd(&gc[tid], hist[tid]); cur[tid] = 0; }
    __syncthreads();
#pragma unroll
    for (int i = 0; i < 8; ++i) {
        if (dst[i] >= 0) {
            int b = dst[i] >> 10;
            int p = base[b] + atomicAdd(&cur[b], 1);
            bb[(size_t)b * BCAP + p] = (uint_t)src[i] | ((uint_t)(dst[i] & 1023) << 16);
        }
    }
}

// ---------------- pass B: per-bucket degree via LDS histogram ----------------
__launch_bounds__(256)
__global__ void bucket_deg(const uint_t* __restrict__ bbuf, const int* __restrict__ gcount,
                           int* __restrict__ degL, int* __restrict__ degN) {
    int rel = blockIdx.y, b = blockIdx.x;
    const uint_t* bb = bbuf + ((size_t)rel * NB + b) * BCAP;
    int n = gcount[rel * NB + b];
    int* deg = rel ? degN : degL;
    __shared__ int ld[1024];
    int tid = threadIdx.x;
    for (int i = tid; i < 1024; i += 256) ld[i] = 0;
    __syncthreads();
    for (int i = tid; i < n; i += 256) atomicAdd(&ld[bb[i] >> 16], 1);
    __syncthreads();
    int dbase = b << 10;
    for (int i = tid; i < 1024; i += 256) {
        int d = dbase + i;
        if (d < NL) deg[d] = ld[i];
    }
}

// ---------------- 3-phase parallel scan over degrees ----------------
__global__ void scan1(const int* __restrict__ degL, const int* __restrict__ degN,
                      int* __restrict__ bsum) {
    int arr = blockIdx.x / SNB, blk = blockIdx.x % SNB;
    const int* deg = arr ? degN : degL;
    int tid = threadIdx.x;
    int base = blk * 1024 + tid * 4;
    int s = 0;
#pragma unroll
    for (int i = 0; i < 4; ++i) { int idx = base + i; if (idx < NL) s += deg[idx]; }
    __shared__ int red[256];
    red[tid] = s;
    __syncthreads();
    for (int d = 128; d > 0; d >>= 1) {
        if (tid < d) red[tid] += red[tid + d];
        __syncthreads();
    }
    if (tid == 0) bsum[blockIdx.x] = red[0];
}

__global__ void scan2(const int* __restrict__ bsum, int* __restrict__ bbase) {
    __shared__ int sh[128];
    int tid = threadIdx.x;
    int v0 = (tid < 2 * SNB) ? bsum[tid] : 0;
    sh[tid] = v0;
    __syncthreads();
    int gstart = (tid < SNB) ? 0 : SNB;
    for (int d = 1; d < 64; d <<= 1) {
        int v = (tid >= gstart + d && tid < 2 * SNB) ? sh[tid - d] : 0;
        __syncthreads();
        sh[tid] += v;
        __syncthreads();
    }
    if (tid < 2 * SNB) bbase[tid] = sh[tid] - v0;
}

__global__ void scan3(const int* __restrict__ degL, const int* __restrict__ degN,
                      const int* __restrict__ bbase,
                      int* __restrict__ offL, int* __restrict__ offN,
                      float* __restrict__ fdegL, float* __restrict__ fdegN) {
    int arr = blockIdx.x / SNB, blk = blockIdx.x % SNB;
    const int* deg = arr ? degN : degL;
    int* off = arr ? offN : offL;
    float* fdeg = arr ? fdegN : fdegL;
    int tid = threadIdx.x;
    int base = blk * 1024 + tid * 4;
    int d4[4]; int s = 0;
#pragma unroll
    for (int i = 0; i < 4; ++i) {
        int idx = base + i;
        d4[i] = (idx < NL) ? deg[idx] : 0;
        s += d4[i];
    }
    __shared__ int part[256];
    part[tid] = s;
    __syncthreads();
    for (int d = 1; d < 256; d <<= 1) {
        int v = (tid >= d) ? part[tid - d] : 0;
        __syncthreads();
        part[tid] += v;
        __syncthreads();
    }
    int run = bbase[blockIdx.x] + part[tid] - s;
#pragma unroll
    for (int i = 0; i < 4; ++i) {
        int idx = base + i;
        if (idx < NL) {
            off[idx] = run; fdeg[idx] = (float)d4[i];
            run += d4[i];
            if (idx == NL - 1) off[NL] = run;
        }
    }
}

// ---------------- pass C: per-bucket CSR fill ----------------
__launch_bounds__(256)
__global__ void bucket_fill(const uint_t* __restrict__ bbuf, const int* __restrict__ gcount,
                            const int* __restrict__ offL, const int* __restrict__ offN,
                            int* __restrict__ adjL, int* __restrict__ adjN) {
    int rel = blockIdx.y, b = blockIdx.x;
    const uint_t* bb = bbuf + ((size_t)rel * NB + b) * BCAP;
    int n = gcount[rel * NB + b];
    const int* off = rel ? offN : offL;
    int* adj = rel ? adjN : adjL;
    __shared__ int lcur[1024];
    int tid = threadIdx.x;
    int dbase = b << 10;
    for (int i = tid; i < 1024; i += 256) {
        int d = dbase + i;
        lcur[i] = (d < NL) ? off[d] : 0;
    }
    __syncthreads();
    for (int i = tid; i < n; i += 256) {
        uint_t v = bb[i];
        int p = atomicAdd(&lcur[v >> 16], 1);
        adj[p] = (int)(v & 0xFFFFu);
    }
}

// ---------------- layer-1 gather (raw 8-col), both relations ----------------
__launch_bounds__(256)
__global__ void gather_sum8_2(const int* __restrict__ offL, const int* __restrict__ adjL,
                              const float* __restrict__ xnode, float* __restrict__ S8l,
                              const int* __restrict__ offN, const int* __restrict__ adjN,
                              const float* __restrict__ xlink, float* __restrict__ S8n) {
    int rel = blockIdx.y;
    const int* off = rel ? offN : offL;
    const int* adj = rel ? adjN : adjL;
    const float* Xr = rel ? xlink : xnode;
    float* S8 = rel ? S8n : S8l;
    int t = blockIdx.x * 256 + threadIdx.x;
    int row = t >> 3, c = t & 7;
    if (row >= NL) return;
    int beg = off[row], end = off[row + 1];
    float acc = 0.f;
    for (int i = beg; i < end; ++i)
        acc += Xr[(size_t)adj[i] * FR + c];
    S8[row * FR + c] = acc;
}

// ---------------- layer-1 fused GEMM, direct per-row (K=24) ----------------
__launch_bounds__(256)
__global__ void gemm_l1(const float* __restrict__ S8l, const float* __restrict__ xlink,
                        const float* __restrict__ dgl,
                        const float* __restrict__ S8n, const float* __restrict__ xnode,
                        const float* __restrict__ dgn,
                        const float* __restrict__ Wstack, const float* __restrict__ bmpAll,
                        const float* __restrict__ bu_nl, const float* __restrict__ bu_ln,
                        ushort_t* __restrict__ outl, ushort_t* __restrict__ outn) {
    int rel = blockIdx.y;
    const float* S8  = rel ? S8n : S8l;
    const float* Xr  = rel ? xnode : xlink;
    const float* deg = rel ? dgn : dgl;
    const float* Ws  = Wstack + (size_t)rel * 384 * H;
    const float* bmp = bmpAll + rel * H;
    const float* bu  = rel ? bu_ln : bu_nl;
    ushort_t* Out = rel ? outn : outl;

    __shared__ float Wl[24][H];
    __shared__ float bf2[2][H];
    int tid = threadIdx.x;
    for (int p = tid; p < 24 * H; p += 256) {
        int kk = p >> 7, c = p & 127;
        int srcrow = (kk >> 3) * 128 + (kk & 7);
        Wl[kk][c] = Ws[srcrow * H + c];
    }
    if (tid < 128) { bf2[0][tid] = bmp[tid]; bf2[1][tid] = bu[tid]; }
    __syncthreads();

    int rl = tid >> 5;
    int cg = tid & 31;
    int row = blockIdx.x * 8 + rl;
    if (row >= NL) return;
    float d = deg[row];
    float a[16];
    *(float4*)(a)      = *(const float4*)(S8 + (size_t)row * FR);
    *(float4*)(a + 4)  = *(const float4*)(S8 + (size_t)row * FR + 4);
    *(float4*)(a + 8)  = *(const float4*)(Xr + (size_t)row * FR);
    *(float4*)(a + 12) = *(const float4*)(Xr + (size_t)row * FR + 4);

    int c0 = cg * 4;
    float acc[4] = {0.f, 0.f, 0.f, 0.f};
#pragma unroll
    for (int k = 0; k < 8; ++k) {
        float4 w = *(const float4*)(&Wl[k][c0]);
        float av = a[k];
        acc[0] += av * w.x; acc[1] += av * w.y; acc[2] += av * w.z; acc[3] += av * w.w;
    }
#pragma unroll
    for (int k = 0; k < 8; ++k) {
        float4 w = *(const float4*)(&Wl[8 + k][c0]);
        float av = d * a[8 + k];
        acc[0] += av * w.x; acc[1] += av * w.y; acc[2] += av * w.z; acc[3] += av * w.w;
    }
#pragma unroll
    for (int k = 0; k < 8; ++k) {
        float4 w = *(const float4*)(&Wl[16 + k][c0]);
        float av = a[8 + k];
        acc[0] += av * w.x; acc[1] += av * w.y; acc[2] += av * w.z; acc[3] += av * w.w;
    }
    uint2 o;
    {
        float v0 = fmaxf(acc[0] + d * bf2[0][c0 + 0] + bf2[1][c0 + 0], 0.f);
        float v1 = fmaxf(acc[1] + d * bf2[0][c0 + 1] + bf2[1][c0 + 1], 0.f);
        float v2 = fmaxf(acc[2] + d * bf2[0][c0 + 2] + bf2[1][c0 + 2], 0.f);
        float v3 = fmaxf(acc[3] + d * bf2[0][c0 + 3] + bf2[1][c0 + 3], 0.f);
        o.x = (unsigned)f2bf(v0) | ((unsigned)f2bf(v1) << 16);
        o.y = (unsigned)f2bf(v2) | ((unsigned)f2bf(v3) << 16);
    }
    *(uint2*)(Out + (size_t)row * H + c0) = o;
}

// ---------------- layer-2 gather (bf16 in, fp32 accum, bf16 out) ----------------
__launch_bounds__(256)
__global__ void gather_bf(const int* __restrict__ offL, const int* __restrict__ adjL,
                          const ushort_t* __restrict__ xnb, ushort_t* __restrict__ Sbl,
                          const int* __restrict__ offN, const int* __restrict__ adjN,
                          const ushort_t* __restrict__ xlb, ushort_t* __restrict__ Sbn) {
    int rel = blockIdx.y;
    const int* off = rel ? offN : offL;
    const int* adj = rel ? adjN : adjL;
    const ushort_t* X = rel ? xlb : xnb;
    ushort_t* Sg = rel ? Sbn : Sbl;
    int row = blockIdx.x * 8 + (threadIdx.x >> 5);
    int lane = threadIdx.x & 31;
    if (row >= NL) return;
    int beg = off[row], end = off[row + 1];
    float a0 = 0.f, a1 = 0.f, a2 = 0.f, a3 = 0.f;
    float b0 = 0.f, b1 = 0.f, b2 = 0.f, b3 = 0.f;
    int i = beg;
    for (; i + 1 < end; i += 2) {
        uint2 ua = *(const uint2*)(X + (size_t)adj[i] * H + lane * 4);
        uint2 ub = *(const uint2*)(X + (size_t)adj[i + 1] * H + lane * 4);
        a0 += bf2f((ushort_t)(ua.x & 0xFFFF)); a1 += bf2f((ushort_t)(ua.x >> 16));
        a2 += bf2f((ushort_t)(ua.y & 0xFFFF)); a3 += bf2f((ushort_t)(ua.y >> 16));
        b0 += bf2f((ushort_t)(ub.x & 0xFFFF)); b1 += bf2f((ushort_t)(ub.x >> 16));
        b2 += bf2f((ushort_t)(ub.y & 0xFFFF)); b3 += bf2f((ushort_t)(ub.y >> 16));
    }
    if (i < end) {
        uint2 ua = *(const uint2*)(X + (size_t)adj[i] * H + lane * 4);
        a0 += bf2f((ushort_t)(ua.x & 0xFFFF)); a1 += bf2f((ushort_t)(ua.x >> 16));
        a2 += bf2f((ushort_t)(ua.y & 0xFFFF)); a3 += bf2f((ushort_t)(ua.y >> 16));
    }
    uint2 o;
    o.x = (unsigned)f2bf(a0 + b0) | ((unsigned)f2bf(a1 + b1) << 16);
    o.y = (unsigned)f2bf(a2 + b2) | ((unsigned)f2bf(a3 + b3) << 16);
    *(uint2*)(Sg + (size_t)row * H + lane * 4) = o;
}

// ---------------- layer-2 fused GEMM via MFMA bf16: 64x128 tile ----------------
#define LSTR 40
__launch_bounds__(256)
__global__ void gemm_mfma(const ushort_t* __restrict__ Sbl, const ushort_t* __restrict__ xlb,
                          const float* __restrict__ dgl,
                          const ushort_t* __restrict__ Sbn, const ushort_t* __restrict__ xnb,
                          const float* __restrict__ dgn,
                          const ushort_t* __restrict__ WbLin, const float* __restrict__ bmpAll,
                          const float* __restrict__ bu_nl, const float* __restrict__ bu_ln,
                          ushort_t* __restrict__ outl, ushort_t* __restrict__ outn, int M) {
    int rel = blockIdx.y;
    const ushort_t* S  = rel ? Sbn : Sbl;
    const ushort_t* X  = rel ? xnb : xlb;
    const float* deg = rel ? dgn : dgl;
    const ushort_t* Wb = WbLin + (size_t)rel * (12 * 4096);
    const float* bmp = bmpAll + (2 + rel) * H;
    const float* bu  = (rel ? bu_ln : bu_nl) + H;
    ushort_t* Out = rel ? outn : outl;

    __shared__ ushort_t A_lds[64 * LSTR];
    __shared__ ushort_t B_lds[128 * LSTR];

    int tid = threadIdx.x;
    int lane = tid & 63;
    int wave = tid >> 6;
    int m0 = blockIdx.x * 64;

    int arow = tid >> 2, kc = tid & 3;
    int grow = m0 + arow;
    bool vr = grow < M;
    float dr = vr ? deg[grow] : 0.f;
    int bc = tid >> 1, bh = tid & 1;

    f32x4 acc[4][2];
#pragma unroll
    for (int i = 0; i < 4; ++i)
#pragma unroll
        for (int j = 0; j < 2; ++j)
            acc[i][j] = (f32x4){0.f, 0.f, 0.f, 0.f};

    int lrow = lane & 15, lg = lane >> 4;

    for (int kt = 0; kt < 12; ++kt) {
        int k0 = kt * 32;
        int piece = k0 >> 7;
        const ushort_t* Asrc = (piece == 0) ? S : X;
        int kin = (k0 & 127) + kc * 8;
        uint4 w = make_uint4(0u, 0u, 0u, 0u);
        if (vr) w = *(const uint4*)(Asrc + (size_t)grow * H + kin);
        if (piece == 1) {
            unsigned* wp = (unsigned*)&w;
#pragma unroll
            for (int q = 0; q < 4; ++q) {
                float v0 = dr * bf2f((ushort_t)(wp[q] & 0xFFFF));
                float v1 = dr * bf2f((ushort_t)(wp[q] >> 16));
                wp[q] = (unsigned)f2bf(v0) | ((unsigned)f2bf(v1) << 16);
            }
        }
        *(uint4*)&A_lds[arow * LSTR + kc * 8] = w;
        {
            uint4 b0 = *(const uint4*)(Wb + (size_t)kt * 4096 + bc * 32 + bh * 16);
            *(uint4*)&B_lds[bc * LSTR + bh * 16] = b0;
            uint4 b1 = *(const uint4*)(Wb + (size_t)kt * 4096 + bc * 32 + bh * 16 + 8);
            *(uint4*)&B_lds[bc * LSTR + bh * 16 + 8] = b1;
        }
        __syncthreads();

        bf16x8 af[4], bfv[2];
#pragma unroll
        for (int mf = 0; mf < 4; ++mf)
            af[mf] = *(const bf16x8*)&A_lds[(mf * 16 + lrow) * LSTR + lg * 8];
#pragma unroll
        for (int nf = 0; nf < 2; ++nf)
            bfv[nf] = *(const bf16x8*)&B_lds[(wave * 32 + nf * 16 + lrow) * LSTR + lg * 8];
#pragma unroll
        for (int mf = 0; mf < 4; ++mf)
#pragma unroll
            for (int nf = 0; nf < 2; ++nf)
                acc[mf][nf] = __builtin_amdgcn_mfma_f32_16x16x32_bf16(
                    af[mf], bfv[nf], acc[mf][nf], 0, 0, 0);
        __syncthreads();
    }

    float bmpv[2], buv[2];
#pragma unroll
    for (int nf = 0; nf < 2; ++nf) {
        int col = wave * 32 + nf * 16 + lrow;
        bmpv[nf] = bmp[col];
        buv[nf] = bu[col];
    }
#pragma unroll
    for (int mf = 0; mf < 4; ++mf) {
#pragma unroll
        for (int r = 0; r < 4; ++r) {
            int row = m0 + mf * 16 + lg * 4 + r;
            if (row < M) {
                float d = deg[row];
#pragma unroll
                for (int nf = 0; nf < 2; ++nf) {
                    int col = wave * 32 + nf * 16 + lrow;
                    float v = acc[mf][nf][r] + d * bmpv[nf] + buv[nf];
                    Out[(size_t)row * H + col] = f2bf(fmaxf(v, 0.f));
                }
            }
        }
    }
}

// ---------------- global mean pool: vectorized, block-reduced fast path ----------------
#define PB 64   // rows per block
__launch_bounds__(256)
__global__ void pool_sum(const ushort_t* __restrict__ xl, const int* __restrict__ batch,
                         float* __restrict__ sums) {
    int base = blockIdx.x * PB;
    int rows = min(PB, NL - base);
    int cg = threadIdx.x & 31;    // 4 cols each
    int rl = threadIdx.x >> 5;    // 8 row-lanes
    int g0 = batch[base];
    int g1 = batch[base + rows - 1];
    if (g0 == g1) {
        // fast path: whole block in one group
        float a0 = 0.f, a1 = 0.f, a2 = 0.f, a3 = 0.f;
        for (int r = rl; r < rows; r += 8) {
            uint2 u = *(const uint2*)(xl + (size_t)(base + r) * H + cg * 4);
            a0 += bf2f((ushort_t)(u.x & 0xFFFF));
            a1 += bf2f((ushort_t)(u.x >> 16));
            a2 += bf2f((ushort_t)(u.y & 0xFFFF));
            a3 += bf2f((ushort_t)(u.y >> 16));
        }
        __shared__ float red[8][H];
        red[rl][cg * 4 + 0] = a0; red[rl][cg * 4 + 1] = a1;
        red[rl][cg * 4 + 2] = a2; red[rl][cg * 4 + 3] = a3;
        __syncthreads();
        if (threadIdx.x < H) {
            int c = threadIdx.x;
            float s = red[0][c] + red[1][c] + red[2][c] + red[3][c]
                    + red[4][c] + red[5][c] + red[6][c] + red[7][c];
            atomicAdd(&sums[g0 * H + c], s);
        }
    } else {
        // slow path: per-thread group tracking
        float a0 = 0.f, a1 = 0.f, a2 = 0.f, a3 = 0.f;
        int cur = -1;
        for (int r = rl; r < rows; r += 8) {
            int row = base + r;
            int g = batch[row];
            if (g != cur) {
                if (cur >= 0) {
                    atomicAdd(&sums[cur * H + cg * 4 + 0], a0);
                    atomicAdd(&sums[cur * H + cg * 4 + 1], a1);
                    atomicAdd(&sums[cur * H + cg * 4 + 2], a2);
                    atomicAdd(&sums[cur * H + cg * 4 + 3], a3);
                }
                a0 = a1 = a2 = a3 = 0.f;
                cur = g;
            }
            uint2 u = *(const uint2*)(xl + (size_t)row * H + cg * 4);
            a0 += bf2f((ushort_t)(u.x & 0xFFFF));
            a1 += bf2f((ushort_t)(u.x >> 16));
            a2 += bf2f((ushort_t)(u.y & 0xFFFF));
            a3 += bf2f((ushort_t)(u.y >> 16));
        }
        if (cur >= 0) {
            atomicAdd(&sums[cur * H + cg * 4 + 0], a0);
            atomicAdd(&sums[cur * H + cg * 4 + 1], a1);
            atomicAdd(&sums[cur * H + cg * 4 + 2], a2);
            atomicAdd(&sums[cur * H + cg * 4 + 3], a3);
        }
    }
}

// ---------------- pool finalize (counts via binary search, no extra kernel) ----------------
__global__ void pool_final(const float* __restrict__ sums, const int* __restrict__ batch,
                           float* __restrict__ out) {
    int idx = blockIdx.x * blockDim.x + threadIdx.x;   // NG*H
    int g = idx / H;
    int lo = 0, hi = NL;
    while (lo < hi) { int mid = (lo + hi) >> 1; if (batch[mid] < g) lo = mid + 1; else hi = mid; }
    int first = lo;
    lo = 0; hi = NL;
    while (lo < hi) { int mid = (lo + hi) >> 1; if (batch[mid] < g + 1) lo = mid + 1; else hi = mid; }
    float cnt = (float)(lo - first);
    out[idx] = sums[idx] / fmaxf(cnt, 1.f);
}

static inline size_t rup(size_t n) { return (n + 15) & ~(size_t)15; }

extern "C" void kernel_launch(void* const* d_in, const int* in_sizes, int n_in,
                              void* d_out, int out_size, void* d_ws, size_t ws_size,
                              hipStream_t stream) {
    const float* x_node = (const float*)d_in[0];
    const float* x_link = (const float*)d_in[1];
    const float* Wm_nl  = (const float*)d_in[2];
    const float* bm_nl  = (const float*)d_in[3];
    const float* Wu_nl  = (const float*)d_in[4];
    const float* bu_nl  = (const float*)d_in[5];
    const float* Wm_ln  = (const float*)d_in[6];
    const float* bm_ln  = (const float*)d_in[7];
    const float* Wu_ln  = (const float*)d_in[8];
    const float* bu_ln  = (const float*)d_in[9];
    const int* nl_edge  = (const int*)d_in[10];
    const int* ln_edge  = (const int*)d_in[11];
    const int* batch_link = (const int*)d_in[12];
    (void)in_sizes; (void)n_in; (void)out_size; (void)ws_size;

    char* wsb = (char*)d_ws;
    size_t o = 0;
    auto alloc = [&](size_t elems) { void* p = wsb + o * 4; o += rup(elems); return p; };
    ushort_t* xnb  = (ushort_t*)alloc((size_t)NN * H / 2);
    ushort_t* xlb  = (ushort_t*)alloc((size_t)NL * H / 2);
    ushort_t* Sbl  = (ushort_t*)alloc((size_t)NL * H / 2);
    ushort_t* Sbn  = (ushort_t*)alloc((size_t)NN * H / 2);
    float* S8l   = (float*)alloc((size_t)NL * FR);
    float* S8n   = (float*)alloc((size_t)NN * FR);
    float* deg_l = (float*)alloc(NL);
    float* deg_n = (float*)alloc(NN);
    int*   idl   = (int*)alloc(NL);
    int*   idn   = (int*)alloc(NN);
    int*   offL  = (int*)alloc(NL + 1);
    int*   offN  = (int*)alloc(NN + 1);
    int*   adjL  = (int*)alloc(NE);
    int*   adjN  = (int*)alloc(NE);
    float* Wstack= (float*)alloc(4L * 384 * H);
    float* bmp   = (float*)alloc(4 * H);
    float* sums  = (float*)alloc(NG * H);
    int*   bsum  = (int*)alloc(2 * SNB);
    int*   bbase = (int*)alloc(2 * SNB);
    ushort_t* WbLin = (ushort_t*)alloc(2 * 12 * 4096 / 2);
    uint_t* bbuf  = (uint_t*)alloc((size_t)2 * NB * BCAP);
    int*    gcount= (int*)alloc(2 * NB);

    hipMemsetAsync(gcount, 0, (size_t)2 * NB * sizeof(int), stream);
    hipMemsetAsync(sums, 0, (size_t)NG * H * sizeof(float), stream);

    precompute_w<<<(4 * (384 * H + H) + 255) / 256, 256, 0, stream>>>(
        Wm_nl, bm_nl, Wu_nl, Wm_ln, bm_ln, Wu_ln, Wstack, bmp, WbLin);

    // ---- CSR build (bucketed) ----
    bucket_scatter<<<dim3((NE + 2047) / 2048, 2), 256, 0, stream>>>(
        nl_edge, ln_edge, bbuf, gcount);
    bucket_deg<<<dim3(NB, 2), 256, 0, stream>>>(bbuf, gcount, idl, idn);
    scan1<<<2 * SNB, 256, 0, stream>>>(idl, idn, bsum);
    scan2<<<1, 128, 0, stream>>>(bsum, bbase);
    scan3<<<2 * SNB, 256, 0, stream>>>(idl, idn, bbase, offL, offN, deg_l, deg_n);
    bucket_fill<<<dim3(NB, 2), 256, 0, stream>>>(bbuf, gcount, offL, offN, adjL, adjN);

    // ---- layer 1 ----
    gather_sum8_2<<<dim3((NL * FR + 255) / 256, 2), 256, 0, stream>>>(
        offL, adjL, x_node, S8l, offN, adjN, x_link, S8n);
    gemm_l1<<<dim3((NL + 7) / 8, 2), 256, 0, stream>>>(
        S8l, x_link, deg_l, S8n, x_node, deg_n, Wstack, bmp, bu_nl, bu_ln, xlb, xnb);

    // ---- layer 2 ----
    gather_bf<<<dim3((NL + 7) / 8, 2), 256, 0, stream>>>(
        offL, adjL, xnb, Sbl, offN, adjN, xlb, Sbn);
    gemm_mfma<<<dim3((NL + 63) / 64, 2), 256, 0, stream>>>(
        Sbl, xlb, deg_l, Sbn, xnb, deg_n, WbLin, bmp, bu_nl, bu_ln, xlb, xnb, NL);

    pool_sum<<<(NL + PB - 1) / PB, 256, 0, stream>>>(xlb, batch_link, sums);
    pool_final<<<(NG * H) / 256, 256, 0, stream>>>(sums, batch_link, (float*)d_out);
}

// Round 11
// 170.616 us; speedup vs baseline: 2.6598x; 1.1487x over previous
//
#include <hip/hip_runtime.h>

// HeteroGNN fused implementation, round 11.
// Algebra: new = relu( S @ W1 + deg.*(x @ W2) + x @ W3 + deg.*bmp + bu )
// Round-11 (fusion pass): gather fused into both GEMMs (Sb/S8 round-trips
// deleted; layer-2 outputs ping-pong to xlb2/xnb2 to avoid cross-relation
// race); B read direct from L2-resident WbLin (k-loop barriers 24->6);
// scan1 deleted (== gcount), scan2 folded into bucket_deg, scan3+fill fused.
// 13 dispatches -> 9.

#define H 128
#define NN 50000
#define NL 50000
#define NE 400000
#define NG 64
#define FR 8
#define NB 49          // dst buckets (dst >> 10)
#define BCAP 12288     // entries per bucket (expected ~8163)
#define TSTR 136       // LDS row stride (bf16 elems): 272B = 17x16B, 2-way banks

typedef __attribute__((ext_vector_type(8))) short bf16x8;
typedef __attribute__((ext_vector_type(4))) float f32x4;
typedef unsigned short ushort_t;
typedef unsigned int uint_t;

__device__ __forceinline__ ushort_t f2bf(float f) {
    union { float f; unsigned u; } v; v.f = f;
    unsigned r = v.u + 0x7FFFu + ((v.u >> 16) & 1u);   // RNE
    return (ushort_t)(r >> 16);
}
__device__ __forceinline__ float bf2f(ushort_t u) {
    union { unsigned u; float f; } v; v.u = ((unsigned)u) << 16; return v.f;
}
// add 8 bf16 (one uint4) into 8 fp32 accumulators
__device__ __forceinline__ void addpk8(float* a, uint4 u) {
    const unsigned* w = (const unsigned*)&u;
#pragma unroll
    for (int q = 0; q < 4; ++q) {
        union { unsigned u; float f; } lo, hi;
        lo.u = w[q] << 16;
        hi.u = w[q] & 0xFFFF0000u;
        a[q * 2 + 0] += lo.f;
        a[q * 2 + 1] += hi.f;
    }
}
__device__ __forceinline__ uint4 pk8(const float* a) {
    uint4 r; unsigned* w = (unsigned*)&r;
#pragma unroll
    for (int q = 0; q < 4; ++q)
        w[q] = (unsigned)f2bf(a[q * 2]) | ((unsigned)f2bf(a[q * 2 + 1]) << 16);
    return r;
}

// ---------------- weight fusion (+ bf16 per-tile layout for layer-2) ----------------
__global__ void precompute_w(const float* __restrict__ Wm_nl, const float* __restrict__ bm_nl,
                             const float* __restrict__ Wu_nl,
                             const float* __restrict__ Wm_ln, const float* __restrict__ bm_ln,
                             const float* __restrict__ Wu_ln,
                             float* __restrict__ Wstack, float* __restrict__ bmp,
                             ushort_t* __restrict__ WbLin) {
    int idx = blockIdx.x * blockDim.x + threadIdx.x;
    const int per = 384 * H + H;
    int c = idx / per, r = idx % per;
    if (c >= 4) return;
    int l = c >> 1, rel = c & 1;
    const float* Wm = (rel ? Wm_ln : Wm_nl) + l * 256 * H;
    const float* Wu = (rel ? Wu_ln : Wu_nl) + l * 256 * H;
    const float* bm = (rel ? bm_ln : bm_nl) + l * H;
    float* Ws = Wstack + c * 384 * H;
    if (r < 384 * H) {
        int t = r / H, j = r % H;
        float val;
        if (t < 256) {
            float acc = 0.f;
            for (int k = 0; k < H; ++k) acc += Wm[t * H + k] * Wu[k * H + j];
            val = acc;
        } else {
            val = Wu[(t - 128) * H + j];
        }
        Ws[t * H + j] = val;
        if (c >= 2) {
            WbLin[(size_t)(c - 2) * (12 * 4096) + (size_t)(t >> 5) * 4096 + j * 32 + (t & 31)]
                = f2bf(val);
        }
    } else {
        int j = r - 384 * H;
        float acc = 0.f;
        for (int k = 0; k < H; ++k) acc += bm[k] * Wu[k * H + j];
        bmp[c * H + j] = acc;
    }
}

// ---------------- pass A: bucket-scatter edges by dst ----------------
__launch_bounds__(256)
__global__ void bucket_scatter(const int* __restrict__ nl, const int* __restrict__ ln,
                               uint_t* __restrict__ bbuf, int* __restrict__ gcount) {
    int rel = blockIdx.y;
    const int* edge = rel ? ln : nl;
    uint_t* bb = bbuf + (size_t)rel * NB * BCAP;
    int* gc = gcount + rel * NB;
    __shared__ int hist[NB], base[NB], cur[NB];
    int tid = threadIdx.x;
    if (tid < NB) hist[tid] = 0;
    __syncthreads();
    int e0 = blockIdx.x * 2048 + tid;
    int src[8], dst[8];
#pragma unroll
    for (int i = 0; i < 8; ++i) {
        int e = e0 + i * 256;
        if (e < NE) {
            src[i] = edge[e];
            dst[i] = edge[NE + e];
            atomicAdd(&hist[dst[i] >> 10], 1);
        } else dst[i] = -1;
    }
    __syncthreads();
    if (tid < NB) { base[tid] = atomicAdd(&gc[tid], hist[tid]); cur[tid] = 0; }
    __syncthreads();
#pragma unroll
    for (int i = 0; i < 8; ++i) {
        if (dst[i] >= 0) {
            int b = dst[i] >> 10;
            int p = base[b] + atomicAdd(&cur[b], 1);
            bb[(size_t)b * BCAP + p] = (uint_t)src[i] | ((uint_t)(dst[i] & 1023) << 16);
        }
    }
}

// ---------------- pass B: per-bucket degree (blocks 0..NB-1) + gcount scan (block NB) ----------------
__launch_bounds__(256)
__global__ void bucket_deg2(const uint_t* __restrict__ bbuf, const int* __restrict__ gcount,
                            int* __restrict__ degL, int* __restrict__ degN,
                            int* __restrict__ bbase) {
    int rel = blockIdx.y, b = blockIdx.x;
    int tid = threadIdx.x;
    if (b == NB) {
        // exclusive scan of gcount[rel*NB .. +NB)
        __shared__ int sh[64];
        int v0 = 0;
        if (tid < 64) { v0 = (tid < NB) ? gcount[rel * NB + tid] : 0; sh[tid] = v0; }
        __syncthreads();
        for (int d = 1; d < 64; d <<= 1) {
            int vv = (tid >= d && tid < 64) ? sh[tid - d] : 0;
            __syncthreads();
            if (tid < 64) sh[tid] += vv;
            __syncthreads();
        }
        if (tid < NB) bbase[rel * NB + tid] = sh[tid] - v0;
        return;
    }
    const uint_t* bb = bbuf + ((size_t)rel * NB + b) * BCAP;
    int n = gcount[rel * NB + b];
    int* deg = rel ? degN : degL;
    __shared__ int ld[1024];
    for (int i = tid; i < 1024; i += 256) ld[i] = 0;
    __syncthreads();
    for (int i = tid; i < n; i += 256) atomicAdd(&ld[bb[i] >> 16], 1);
    __syncthreads();
    int dbase = b << 10;
    for (int i = tid; i < 1024; i += 256) {
        int d = dbase + i;
        if (d < NL) deg[d] = ld[i];
    }
}

// ---------------- pass C: per-bucket offset scan + CSR fill (fused) ----------------
__launch_bounds__(256)
__global__ void scan_fill(const int* __restrict__ degL, const int* __restrict__ degN,
                          const int* __restrict__ bbase,
                          int* __restrict__ offL, int* __restrict__ offN,
                          float* __restrict__ fdegL, float* __restrict__ fdegN,
                          const uint_t* __restrict__ bbuf, const int* __restrict__ gcount,
                          int* __restrict__ adjL, int* __restrict__ adjN) {
    int arr = blockIdx.y, blk = blockIdx.x;
    const int* deg = arr ? degN : degL;
    int* off = arr ? offN : offL;
    float* fdeg = arr ? fdegN : fdegL;
    int* adj = arr ? adjN : adjL;
    const uint_t* bb = bbuf + ((size_t)arr * NB + blk) * BCAP;
    int n = gcount[arr * NB + blk];

    __shared__ int part[256];
    __shared__ int lcur[1024];
    int tid = threadIdx.x;
    int base = blk * 1024 + tid * 4;
    int d4[4]; int s = 0;
#pragma unroll
    for (int i = 0; i < 4; ++i) {
        int idx = base + i;
        d4[i] = (idx < NL) ? deg[idx] : 0;
        s += d4[i];
    }
    part[tid] = s;
    __syncthreads();
    for (int d = 1; d < 256; d <<= 1) {
        int v = (tid >= d) ? part[tid - d] : 0;
        __syncthreads();
        part[tid] += v;
        __syncthreads();
    }
    int run = bbase[arr * NB + blk] + part[tid] - s;
#pragma unroll
    for (int i = 0; i < 4; ++i) {
        int idx = base + i;
        lcur[tid * 4 + i] = run;
        if (idx < NL) {
            off[idx] = run; fdeg[idx] = (float)d4[i];
            run += d4[i];
            if (idx == NL - 1) off[NL] = run;
        }
    }
    __syncthreads();
    for (int i = tid; i < n; i += 256) {
        uint_t v = bb[i];
        int p = atomicAdd(&lcur[v >> 16], 1);
        adj[p] = (int)(v & 0xFFFFu);
    }
}

// ---------------- layer-1: fused gather (raw 8-col) + GEMM (K=24), bf16 out ----------------
// 16 rows/block; gather from read-only raw inputs -> no cross-relation race.
__launch_bounds__(256)
__global__ void gemm_l1_f(const int* __restrict__ offL, const int* __restrict__ adjL,
                          const int* __restrict__ offN, const int* __restrict__ adjN,
                          const float* __restrict__ x_node, const float* __restrict__ x_link,
                          const float* __restrict__ dgl, const float* __restrict__ dgn,
                          const float* __restrict__ Wstack, const float* __restrict__ bmpAll,
                          const float* __restrict__ bu_nl, const float* __restrict__ bu_ln,
                          ushort_t* __restrict__ outl, ushort_t* __restrict__ outn) {
    int rel = blockIdx.y;
    const int* off = rel ? offN : offL;
    const int* adj = rel ? adjN : adjL;
    const float* Xg = rel ? x_link : x_node;   // gather source (opposite type, raw)
    const float* Xo = rel ? x_node : x_link;   // own raw features
    const float* deg = rel ? dgn : dgl;
    const float* Ws  = Wstack + (size_t)rel * 384 * H;
    const float* bmp = bmpAll + rel * H;
    const float* bu  = rel ? bu_ln : bu_nl;
    ushort_t* Out = rel ? outn : outl;

    __shared__ float Wl[24][H];
    __shared__ float bf2s[2][H];
    __shared__ float G[16][2][8];
    __shared__ float S8r[16][8];

    int tid = threadIdx.x;
    for (int p = tid; p < 24 * H; p += 256) {
        int kk = p >> 7, c = p & 127;
        int srcrow = (kk >> 3) * 128 + (kk & 7);
        Wl[kk][c] = Ws[srcrow * H + c];
    }
    if (tid < 128) { bf2s[0][tid] = bmp[tid]; bf2s[1][tid] = bu[tid]; }

    int rl = tid >> 4;       // 16 rows per block
    int t16 = tid & 15;
    int row = blockIdx.x * 16 + rl;          // grid 3125 -> exact
    // gather: c = t16&7 column, q = t16>>3 (0/1) neighbor-half
    {
        int c = t16 & 7, q = t16 >> 3;
        int beg = off[row], end = off[row + 1];
        float s = 0.f;
        for (int i = beg + q; i < end; i += 2)
            s += Xg[(size_t)adj[i] * FR + c];
        G[rl][q][c] = s;
    }
    __syncthreads();
    if (t16 < 8) S8r[rl][t16] = G[rl][0][t16] + G[rl][1][t16];
    __syncthreads();

    float d = deg[row];
    float a[16];
#pragma unroll
    for (int j = 0; j < 8; ++j) a[j] = S8r[rl][j];
    *(float4*)(a + 8)  = *(const float4*)(Xo + (size_t)row * FR);
    *(float4*)(a + 12) = *(const float4*)(Xo + (size_t)row * FR + 4);

    int c0 = t16 * 8;
    float acc[8] = {};
#pragma unroll
    for (int k = 0; k < 8; ++k) {
        float4 w0 = *(const float4*)(&Wl[k][c0]);
        float4 w1 = *(const float4*)(&Wl[k][c0 + 4]);
        float av = a[k];
        acc[0] += av * w0.x; acc[1] += av * w0.y; acc[2] += av * w0.z; acc[3] += av * w0.w;
        acc[4] += av * w1.x; acc[5] += av * w1.y; acc[6] += av * w1.z; acc[7] += av * w1.w;
    }
#pragma unroll
    for (int k = 0; k < 8; ++k) {
        float4 w0 = *(const float4*)(&Wl[8 + k][c0]);
        float4 w1 = *(const float4*)(&Wl[8 + k][c0 + 4]);
        float av = d * a[8 + k];
        acc[0] += av * w0.x; acc[1] += av * w0.y; acc[2] += av * w0.z; acc[3] += av * w0.w;
        acc[4] += av * w1.x; acc[5] += av * w1.y; acc[6] += av * w1.z; acc[7] += av * w1.w;
    }
#pragma unroll
    for (int k = 0; k < 8; ++k) {
        float4 w0 = *(const float4*)(&Wl[16 + k][c0]);
        float4 w1 = *(const float4*)(&Wl[16 + k][c0 + 4]);
        float av = a[8 + k];
        acc[0] += av * w0.x; acc[1] += av * w0.y; acc[2] += av * w0.z; acc[3] += av * w0.w;
        acc[4] += av * w1.x; acc[5] += av * w1.y; acc[6] += av * w1.z; acc[7] += av * w1.w;
    }

    float o[8];
#pragma unroll
    for (int j = 0; j < 8; ++j)
        o[j] = fmaxf(acc[j] + d * bf2s[0][c0 + j] + bf2s[1][c0 + j], 0.f);
    *(uint4*)(Out + (size_t)row * H + c0) = pk8(o);
}

// ---------------- layer-2: fused gather + MFMA GEMM, phased single LDS tile ----------------
// Out2 = relu([S | deg.*X | X]_bf16 @ W_bf16 + deg.*bmp + bu); 64x128 tile.
// S gathered in-block from opposite-type state; outputs go to NEW buffers
// (xlb2/xnb2) because rel0 gathers xnb while rel1 would write it in-place.
__launch_bounds__(256)
__global__ void gemm_mfma_f(const int* __restrict__ offL, const int* __restrict__ adjL,
                            const int* __restrict__ offN, const int* __restrict__ adjN,
                            const ushort_t* __restrict__ xlb, const ushort_t* __restrict__ xnb,
                            const float* __restrict__ dgl, const float* __restrict__ dgn,
                            const ushort_t* __restrict__ WbLin, const float* __restrict__ bmpAll,
                            const float* __restrict__ bu_nl, const float* __restrict__ bu_ln,
                            ushort_t* __restrict__ outl2, ushort_t* __restrict__ outn2, int M) {
    int rel = blockIdx.y;
    const int* off = rel ? offN : offL;
    const int* adj = rel ? adjN : adjL;
    const ushort_t* Xg = rel ? xlb : xnb;   // gather source (opposite type)
    const ushort_t* Xo = rel ? xnb : xlb;   // own rows
    const float* deg = rel ? dgn : dgl;
    const ushort_t* Wb = WbLin + (size_t)rel * (12 * 4096);
    const float* bmp = bmpAll + (2 + rel) * H;
    const float* bu  = (rel ? bu_ln : bu_nl) + H;   // layer index 1
    ushort_t* Out = rel ? outn2 : outl2;

    __shared__ ushort_t T[64 * TSTR];   // 17.4 KB, reused S -> deg*X -> X

    int tid = threadIdx.x;
    int lane = tid & 63;
    int wave = tid >> 6;
    int m0 = blockIdx.x * 64;
    int lrow = lane & 15, lg = lane >> 4;

    // staging map: 4 threads per row, 32 cols each
    int trow = tid >> 2, chunk = tid & 3;
    int grow = m0 + trow;
    bool vr = grow < M;
    int cbase = chunk * 32;

    // ---- phase A: gather S (fp32 accum) -> bf16 tile ----
    {
        float a[32];
#pragma unroll
        for (int j = 0; j < 32; ++j) a[j] = 0.f;
        if (vr) {
            int beg = off[grow], end = off[grow + 1];
            for (int i = beg; i < end; ++i) {
                const uint4* p = (const uint4*)(Xg + (size_t)adj[i] * H + cbase);
                addpk8(a + 0,  p[0]);
                addpk8(a + 8,  p[1]);
                addpk8(a + 16, p[2]);
                addpk8(a + 24, p[3]);
            }
        }
        uint4* dst = (uint4*)&T[trow * TSTR + cbase];
        dst[0] = pk8(a + 0); dst[1] = pk8(a + 8);
        dst[2] = pk8(a + 16); dst[3] = pk8(a + 24);
    }

    f32x4 acc[4][2];
#pragma unroll
    for (int i = 0; i < 4; ++i)
#pragma unroll
        for (int j = 0; j < 2; ++j)
            acc[i][j] = (f32x4){0.f, 0.f, 0.f, 0.f};

    __syncthreads();
    // ---- kts 0..3: piece S ----
#pragma unroll
    for (int kk = 0; kk < 4; ++kk) {
        bf16x8 af[4], bfv[2];
#pragma unroll
        for (int mf = 0; mf < 4; ++mf)
            af[mf] = *(const bf16x8*)&T[(mf * 16 + lrow) * TSTR + kk * 32 + lg * 8];
#pragma unroll
        for (int nf = 0; nf < 2; ++nf)
            bfv[nf] = *(const bf16x8*)(Wb + (size_t)kk * 4096
                        + (wave * 32 + nf * 16 + lrow) * 32 + lg * 8);
#pragma unroll
        for (int mf = 0; mf < 4; ++mf)
#pragma unroll
            for (int nf = 0; nf < 2; ++nf)
                acc[mf][nf] = __builtin_amdgcn_mfma_f32_16x16x32_bf16(
                    af[mf], bfv[nf], acc[mf][nf], 0, 0, 0);
    }
    __syncthreads();

    // ---- phase B: own x row (stash) -> deg-scaled tile ----
    uint4 xs[4];
    {
        if (vr) {
            const uint4* p = (const uint4*)(Xo + (size_t)grow * H + cbase);
            xs[0] = p[0]; xs[1] = p[1]; xs[2] = p[2]; xs[3] = p[3];
        } else {
            xs[0] = xs[1] = xs[2] = xs[3] = make_uint4(0u, 0u, 0u, 0u);
        }
        float dr = vr ? deg[grow] : 0.f;
        uint4* dst = (uint4*)&T[trow * TSTR + cbase];
#pragma unroll
        for (int v = 0; v < 4; ++v) {
            uint4 w = xs[v];
            unsigned* wp = (unsigned*)&w;
#pragma unroll
            for (int q = 0; q < 4; ++q) {
                float v0 = dr * bf2f((ushort_t)(wp[q] & 0xFFFF));
                float v1 = dr * bf2f((ushort_t)(wp[q] >> 16));
                wp[q] = (unsigned)f2bf(v0) | ((unsigned)f2bf(v1) << 16);
            }
            dst[v] = w;
        }
    }
    __syncthreads();
    // ---- kts 4..7: piece deg*X ----
#pragma unroll
    for (int kk = 0; kk < 4; ++kk) {
        bf16x8 af[4], bfv[2];
#pragma unroll
        for (int mf = 0; mf < 4; ++mf)
            af[mf] = *(const bf16x8*)&T[(mf * 16 + lrow) * TSTR + kk * 32 + lg * 8];
#pragma unroll
        for (int nf = 0; nf < 2; ++nf)
            bfv[nf] = *(const bf16x8*)(Wb + (size_t)(4 + kk) * 4096
                        + (wave * 32 + nf * 16 + lrow) * 32 + lg * 8);
#pragma unroll
        for (int mf = 0; mf < 4; ++mf)
#pragma unroll
            for (int nf = 0; nf < 2; ++nf)
                acc[mf][nf] = __builtin_amdgcn_mfma_f32_16x16x32_bf16(
                    af[mf], bfv[nf], acc[mf][nf], 0, 0, 0);
    }
    __syncthreads();

    // ---- phase C: unscaled x tile (from stash) ----
    {
        uint4* dst = (uint4*)&T[trow * TSTR + cbase];
        dst[0] = xs[0]; dst[1] = xs[1]; dst[2] = xs[2]; dst[3] = xs[3];
    }
    __syncthreads();
    // ---- kts 8..11: piece X ----
#pragma unroll
    for (int kk = 0; kk < 4; ++kk) {
        bf16x8 af[4], bfv[2];
#pragma unroll
        for (int mf = 0; mf < 4; ++mf)
            af[mf] = *(const bf16x8*)&T[(mf * 16 + lrow) * TSTR + kk * 32 + lg * 8];
#pragma unroll
        for (int nf = 0; nf < 2; ++nf)
            bfv[nf] = *(const bf16x8*)(Wb + (size_t)(8 + kk) * 4096
                        + (wave * 32 + nf * 16 + lrow) * 32 + lg * 8);
#pragma unroll
        for (int mf = 0; mf < 4; ++mf)
#pragma unroll
            for (int nf = 0; nf < 2; ++nf)
                acc[mf][nf] = __builtin_amdgcn_mfma_f32_16x16x32_bf16(
                    af[mf], bfv[nf], acc[mf][nf], 0, 0, 0);
    }

    // ---- epilogue ----
    float bmpv[2], buv[2];
#pragma unroll
    for (int nf = 0; nf < 2; ++nf) {
        int col = wave * 32 + nf * 16 + lrow;
        bmpv[nf] = bmp[col];
        buv[nf] = bu[col];
    }
#pragma unroll
    for (int mf = 0; mf < 4; ++mf) {
#pragma unroll
        for (int r = 0; r < 4; ++r) {
            int row = m0 + mf * 16 + lg * 4 + r;
            if (row < M) {
                float d = deg[row];
#pragma unroll
                for (int nf = 0; nf < 2; ++nf) {
                    int col = wave * 32 + nf * 16 + lrow;
                    float v = acc[mf][nf][r] + d * bmpv[nf] + buv[nf];
                    Out[(size_t)row * H + col] = f2bf(fmaxf(v, 0.f));
                }
            }
        }
    }
}

// ---------------- global mean pool ----------------
#define PB 64
__launch_bounds__(256)
__global__ void pool_sum(const ushort_t* __restrict__ xl, const int* __restrict__ batch,
                         float* __restrict__ sums) {
    int base = blockIdx.x * PB;
    int rows = min(PB, NL - base);
    int cg = threadIdx.x & 31;
    int rl = threadIdx.x >> 5;
    int g0 = batch[base];
    int g1 = batch[base + rows - 1];
    if (g0 == g1) {
        float a0 = 0.f, a1 = 0.f, a2 = 0.f, a3 = 0.f;
        for (int r = rl; r < rows; r += 8) {
            uint2 u = *(const uint2*)(xl + (size_t)(base + r) * H + cg * 4);
            a0 += bf2f((ushort_t)(u.x & 0xFFFF));
            a1 += bf2f((ushort_t)(u.x >> 16));
            a2 += bf2f((ushort_t)(u.y & 0xFFFF));
            a3 += bf2f((ushort_t)(u.y >> 16));
        }
        __shared__ float red[8][H];
        red[rl][cg * 4 + 0] = a0; red[rl][cg * 4 + 1] = a1;
        red[rl][cg * 4 + 2] = a2; red[rl][cg * 4 + 3] = a3;
        __syncthreads();
        if (threadIdx.x < H) {
            int c = threadIdx.x;
            float s = red[0][c] + red[1][c] + red[2][c] + red[3][c]
                    + red[4][c] + red[5][c] + red[6][c] + red[7][c];
            atomicAdd(&sums[g0 * H + c], s);
        }
    } else {
        float a0 = 0.f, a1 = 0.f, a2 = 0.f, a3 = 0.f;
        int cur = -1;
        for (int r = rl; r < rows; r += 8) {
            int row = base + r;
            int g = batch[row];
            if (g != cur) {
                if (cur >= 0) {
                    atomicAdd(&sums[cur * H + cg * 4 + 0], a0);
                    atomicAdd(&sums[cur * H + cg * 4 + 1], a1);
                    atomicAdd(&sums[cur * H + cg * 4 + 2], a2);
                    atomicAdd(&sums[cur * H + cg * 4 + 3], a3);
                }
                a0 = a1 = a2 = a3 = 0.f;
                cur = g;
            }
            uint2 u = *(const uint2*)(xl + (size_t)row * H + cg * 4);
            a0 += bf2f((ushort_t)(u.x & 0xFFFF));
            a1 += bf2f((ushort_t)(u.x >> 16));
            a2 += bf2f((ushort_t)(u.y & 0xFFFF));
            a3 += bf2f((ushort_t)(u.y >> 16));
        }
        if (cur >= 0) {
            atomicAdd(&sums[cur * H + cg * 4 + 0], a0);
            atomicAdd(&sums[cur * H + cg * 4 + 1], a1);
            atomicAdd(&sums[cur * H + cg * 4 + 2], a2);
            atomicAdd(&sums[cur * H + cg * 4 + 3], a3);
        }
    }
}

__global__ void pool_final(const float* __restrict__ sums, const int* __restrict__ batch,
                           float* __restrict__ out) {
    int idx = blockIdx.x * blockDim.x + threadIdx.x;
    int g = idx / H;
    int lo = 0, hi = NL;
    while (lo < hi) { int mid = (lo + hi) >> 1; if (batch[mid] < g) lo = mid + 1; else hi = mid; }
    int first = lo;
    lo = 0; hi = NL;
    while (lo < hi) { int mid = (lo + hi) >> 1; if (batch[mid] < g + 1) lo = mid + 1; else hi = mid; }
    float cnt = (float)(lo - first);
    out[idx] = sums[idx] / fmaxf(cnt, 1.f);
}

static inline size_t rup(size_t n) { return (n + 15) & ~(size_t)15; }

extern "C" void kernel_launch(void* const* d_in, const int* in_sizes, int n_in,
                              void* d_out, int out_size, void* d_ws, size_t ws_size,
                              hipStream_t stream) {
    const float* x_node = (const float*)d_in[0];
    const float* x_link = (const float*)d_in[1];
    const float* Wm_nl  = (const float*)d_in[2];
    const float* bm_nl  = (const float*)d_in[3];
    const float* Wu_nl  = (const float*)d_in[4];
    const float* bu_nl  = (const float*)d_in[5];
    const float* Wm_ln  = (const float*)d_in[6];
    const float* bm_ln  = (const float*)d_in[7];
    const float* Wu_ln  = (const float*)d_in[8];
    const float* bu_ln  = (const float*)d_in[9];
    const int* nl_edge  = (const int*)d_in[10];
    const int* ln_edge  = (const int*)d_in[11];
    const int* batch_link = (const int*)d_in[12];
    (void)in_sizes; (void)n_in; (void)out_size; (void)ws_size;

    char* wsb = (char*)d_ws;
    size_t o = 0;
    auto alloc = [&](size_t elems) { void* p = wsb + o * 4; o += rup(elems); return p; };
    ushort_t* xnb  = (ushort_t*)alloc((size_t)NN * H / 2);   // bf16 state after layer 1
    ushort_t* xlb  = (ushort_t*)alloc((size_t)NL * H / 2);
    ushort_t* xnb2 = (ushort_t*)alloc((size_t)NN * H / 2);   // after layer 2 (ping-pong)
    ushort_t* xlb2 = (ushort_t*)alloc((size_t)NL * H / 2);
    float* deg_l = (float*)alloc(NL);
    float* deg_n = (float*)alloc(NN);
    int*   idl   = (int*)alloc(NL);
    int*   idn   = (int*)alloc(NN);
    int*   offL  = (int*)alloc(NL + 1);
    int*   offN  = (int*)alloc(NN + 1);
    int*   adjL  = (int*)alloc(NE);
    int*   adjN  = (int*)alloc(NE);
    float* Wstack= (float*)alloc(4L * 384 * H);
    float* bmp   = (float*)alloc(4 * H);
    ushort_t* WbLin = (ushort_t*)alloc(2 * 12 * 4096 / 2);
    uint_t* bbuf  = (uint_t*)alloc((size_t)2 * NB * BCAP);
    int*   bbase = (int*)alloc(2 * NB);
    float* sums  = (float*)alloc(NG * H);    // NG*H = 8192 (16-aligned)
    int*   gcount= (int*)alloc(2 * NB);      // contiguous after sums -> one memset

    // one memset covers sums (32KB) + gcount (392B)
    hipMemsetAsync(sums, 0, ((size_t)NG * H + rup(2 * NB)) * 4, stream);

    precompute_w<<<(4 * (384 * H + H) + 255) / 256, 256, 0, stream>>>(
        Wm_nl, bm_nl, Wu_nl, Wm_ln, bm_ln, Wu_ln, Wstack, bmp, WbLin);

    // ---- CSR build ----
    bucket_scatter<<<dim3((NE + 2047) / 2048, 2), 256, 0, stream>>>(
        nl_edge, ln_edge, bbuf, gcount);
    bucket_deg2<<<dim3(NB + 1, 2), 256, 0, stream>>>(bbuf, gcount, idl, idn, bbase);
    scan_fill<<<dim3(NB, 2), 256, 0, stream>>>(
        idl, idn, bbase, offL, offN, deg_l, deg_n, bbuf, gcount, adjL, adjN);

    // ---- layer 1 (fused gather + GEMM) ----
    gemm_l1_f<<<dim3(NL / 16, 2), 256, 0, stream>>>(
        offL, adjL, offN, adjN, x_node, x_link, deg_l, deg_n,
        Wstack, bmp, bu_nl, bu_ln, xlb, xnb);

    // ---- layer 2 (fused gather + MFMA GEMM) ----
    gemm_mfma_f<<<dim3((NL + 63) / 64, 2), 256, 0, stream>>>(
        offL, adjL, offN, adjN, xlb, xnb, deg_l, deg_n,
        WbLin, bmp, bu_nl, bu_ln, xlb2, xnb2, NL);

    // ---- pool ----
    pool_sum<<<(NL + PB - 1) / PB, 256, 0, stream>>>(xlb2, batch_link, sums);
    pool_final<<<(NG * H) / 256, 256, 0, stream>>>(sums, batch_link, (float*)d_out);
}

// Round 12
// 139.155 us; speedup vs baseline: 3.2611x; 1.2261x over previous
//
#include <hip/hip_runtime.h>

// HeteroGNN fused implementation, round 12.
// Algebra: new = relu( S @ W1 + deg.*(x @ W2) + x @ W3 + deg.*bmp + bu )
// Round-12: (a) layer-2 NODE update deleted -- it's dead code (output = pool
// of link state only); (b) layer-2 kernel re-tiled 64->32 rows with 8-thread/
// row 2-unrolled gather (latency-bound phase: 2x blocks, 4 loads in flight);
// (c) pool fused into the epilogue (shfl-reduced fp32, atomicAdd to sums) --
// xlb2/xnb2 buffers, their writes, and pool_sum all deleted. 7 dispatches.

#define H 128
#define NN 50000
#define NL 50000
#define NE 400000
#define NG 64
#define FR 8
#define NB 49          // dst buckets (dst >> 10)
#define BCAP 12288     // entries per bucket (expected ~8163)
#define TSTR 136       // LDS row stride (bf16 elems)
#define TROWS 32       // layer-2 tile rows

typedef __attribute__((ext_vector_type(8))) short bf16x8;
typedef __attribute__((ext_vector_type(4))) float f32x4;
typedef unsigned short ushort_t;
typedef unsigned int uint_t;

__device__ __forceinline__ ushort_t f2bf(float f) {
    union { float f; unsigned u; } v; v.f = f;
    unsigned r = v.u + 0x7FFFu + ((v.u >> 16) & 1u);   // RNE
    return (ushort_t)(r >> 16);
}
__device__ __forceinline__ float bf2f(ushort_t u) {
    union { unsigned u; float f; } v; v.u = ((unsigned)u) << 16; return v.f;
}
__device__ __forceinline__ void addpk8(float* a, uint4 u) {
    const unsigned* w = (const unsigned*)&u;
#pragma unroll
    for (int q = 0; q < 4; ++q) {
        union { unsigned u; float f; } lo, hi;
        lo.u = w[q] << 16;
        hi.u = w[q] & 0xFFFF0000u;
        a[q * 2 + 0] += lo.f;
        a[q * 2 + 1] += hi.f;
    }
}
__device__ __forceinline__ uint4 pk8(const float* a) {
    uint4 r; unsigned* w = (unsigned*)&r;
#pragma unroll
    for (int q = 0; q < 4; ++q)
        w[q] = (unsigned)f2bf(a[q * 2]) | ((unsigned)f2bf(a[q * 2 + 1]) << 16);
    return r;
}

// ---------------- weight fusion (+ bf16 per-tile layout for layer-2) ----------------
__global__ void precompute_w(const float* __restrict__ Wm_nl, const float* __restrict__ bm_nl,
                             const float* __restrict__ Wu_nl,
                             const float* __restrict__ Wm_ln, const float* __restrict__ bm_ln,
                             const float* __restrict__ Wu_ln,
                             float* __restrict__ Wstack, float* __restrict__ bmp,
                             ushort_t* __restrict__ WbLin) {
    int idx = blockIdx.x * blockDim.x + threadIdx.x;
    const int per = 384 * H + H;
    int c = idx / per, r = idx % per;
    if (c >= 4) return;
    int l = c >> 1, rel = c & 1;
    const float* Wm = (rel ? Wm_ln : Wm_nl) + l * 256 * H;
    const float* Wu = (rel ? Wu_ln : Wu_nl) + l * 256 * H;
    const float* bm = (rel ? bm_ln : bm_nl) + l * H;
    float* Ws = Wstack + c * 384 * H;
    if (r < 384 * H) {
        int t = r / H, j = r % H;
        float val;
        if (t < 256) {
            float acc = 0.f;
            for (int k = 0; k < H; ++k) acc += Wm[t * H + k] * Wu[k * H + j];
            val = acc;
        } else {
            val = Wu[(t - 128) * H + j];
        }
        Ws[t * H + j] = val;
        if (c == 2) {
            // layer-2 link-update weights, bf16 per-tile layout
            WbLin[(size_t)(t >> 5) * 4096 + j * 32 + (t & 31)] = f2bf(val);
        }
    } else {
        int j = r - 384 * H;
        float acc = 0.f;
        for (int k = 0; k < H; ++k) acc += bm[k] * Wu[k * H + j];
        bmp[c * H + j] = acc;
    }
}

// ---------------- pass A: bucket-scatter edges by dst ----------------
__launch_bounds__(256)
__global__ void bucket_scatter(const int* __restrict__ nl, const int* __restrict__ ln,
                               uint_t* __restrict__ bbuf, int* __restrict__ gcount) {
    int rel = blockIdx.y;
    const int* edge = rel ? ln : nl;
    uint_t* bb = bbuf + (size_t)rel * NB * BCAP;
    int* gc = gcount + rel * NB;
    __shared__ int hist[NB], base[NB], cur[NB];
    int tid = threadIdx.x;
    if (tid < NB) hist[tid] = 0;
    __syncthreads();
    int e0 = blockIdx.x * 2048 + tid;
    int src[8], dst[8];
#pragma unroll
    for (int i = 0; i < 8; ++i) {
        int e = e0 + i * 256;
        if (e < NE) {
            src[i] = edge[e];
            dst[i] = edge[NE + e];
            atomicAdd(&hist[dst[i] >> 10], 1);
        } else dst[i] = -1;
    }
    __syncthreads();
    if (tid < NB) { base[tid] = atomicAdd(&gc[tid], hist[tid]); cur[tid] = 0; }
    __syncthreads();
#pragma unroll
    for (int i = 0; i < 8; ++i) {
        if (dst[i] >= 0) {
            int b = dst[i] >> 10;
            int p = base[b] + atomicAdd(&cur[b], 1);
            bb[(size_t)b * BCAP + p] = (uint_t)src[i] | ((uint_t)(dst[i] & 1023) << 16);
        }
    }
}

// ---------------- pass B: per-bucket degree + gcount scan (block NB) ----------------
__launch_bounds__(256)
__global__ void bucket_deg2(const uint_t* __restrict__ bbuf, const int* __restrict__ gcount,
                            int* __restrict__ degL, int* __restrict__ degN,
                            int* __restrict__ bbase) {
    int rel = blockIdx.y, b = blockIdx.x;
    int tid = threadIdx.x;
    if (b == NB) {
        __shared__ int sh[64];
        int v0 = 0;
        if (tid < 64) { v0 = (tid < NB) ? gcount[rel * NB + tid] : 0; sh[tid] = v0; }
        __syncthreads();
        for (int d = 1; d < 64; d <<= 1) {
            int vv = (tid >= d && tid < 64) ? sh[tid - d] : 0;
            __syncthreads();
            if (tid < 64) sh[tid] += vv;
            __syncthreads();
        }
        if (tid < NB) bbase[rel * NB + tid] = sh[tid] - v0;
        return;
    }
    const uint_t* bb = bbuf + ((size_t)rel * NB + b) * BCAP;
    int n = gcount[rel * NB + b];
    int* deg = rel ? degN : degL;
    __shared__ int ld[1024];
    for (int i = tid; i < 1024; i += 256) ld[i] = 0;
    __syncthreads();
    for (int i = tid; i < n; i += 256) atomicAdd(&ld[bb[i] >> 16], 1);
    __syncthreads();
    int dbase = b << 10;
    for (int i = tid; i < 1024; i += 256) {
        int d = dbase + i;
        if (d < NL) deg[d] = ld[i];
    }
}

// ---------------- pass C: per-bucket offset scan + CSR fill (fused) ----------------
__launch_bounds__(256)
__global__ void scan_fill(const int* __restrict__ degL, const int* __restrict__ degN,
                          const int* __restrict__ bbase,
                          int* __restrict__ offL, int* __restrict__ offN,
                          float* __restrict__ fdegL, float* __restrict__ fdegN,
                          const uint_t* __restrict__ bbuf, const int* __restrict__ gcount,
                          int* __restrict__ adjL, int* __restrict__ adjN) {
    int arr = blockIdx.y, blk = blockIdx.x;
    const int* deg = arr ? degN : degL;
    int* off = arr ? offN : offL;
    float* fdeg = arr ? fdegN : fdegL;
    int* adj = arr ? adjN : adjL;
    const uint_t* bb = bbuf + ((size_t)arr * NB + blk) * BCAP;
    int n = gcount[arr * NB + blk];

    __shared__ int part[256];
    __shared__ int lcur[1024];
    int tid = threadIdx.x;
    int base = blk * 1024 + tid * 4;
    int d4[4]; int s = 0;
#pragma unroll
    for (int i = 0; i < 4; ++i) {
        int idx = base + i;
        d4[i] = (idx < NL) ? deg[idx] : 0;
        s += d4[i];
    }
    part[tid] = s;
    __syncthreads();
    for (int d = 1; d < 256; d <<= 1) {
        int v = (tid >= d) ? part[tid - d] : 0;
        __syncthreads();
        part[tid] += v;
        __syncthreads();
    }
    int run = bbase[arr * NB + blk] + part[tid] - s;
#pragma unroll
    for (int i = 0; i < 4; ++i) {
        int idx = base + i;
        lcur[tid * 4 + i] = run;
        if (idx < NL) {
            off[idx] = run; fdeg[idx] = (float)d4[i];
            run += d4[i];
            if (idx == NL - 1) off[NL] = run;
        }
    }
    __syncthreads();
    for (int i = tid; i < n; i += 256) {
        uint_t v = bb[i];
        int p = atomicAdd(&lcur[v >> 16], 1);
        adj[p] = (int)(v & 0xFFFFu);
    }
}

// ---------------- layer-1: fused gather (raw 8-col) + GEMM (K=24), bf16 out ----------------
__launch_bounds__(256)
__global__ void gemm_l1_f(const int* __restrict__ offL, const int* __restrict__ adjL,
                          const int* __restrict__ offN, const int* __restrict__ adjN,
                          const float* __restrict__ x_node, const float* __restrict__ x_link,
                          const float* __restrict__ dgl, const float* __restrict__ dgn,
                          const float* __restrict__ Wstack, const float* __restrict__ bmpAll,
                          const float* __restrict__ bu_nl, const float* __restrict__ bu_ln,
                          ushort_t* __restrict__ outl, ushort_t* __restrict__ outn) {
    int rel = blockIdx.y;
    const int* off = rel ? offN : offL;
    const int* adj = rel ? adjN : adjL;
    const float* Xg = rel ? x_link : x_node;
    const float* Xo = rel ? x_node : x_link;
    const float* deg = rel ? dgn : dgl;
    const float* Ws  = Wstack + (size_t)rel * 384 * H;
    const float* bmp = bmpAll + rel * H;
    const float* bu  = rel ? bu_ln : bu_nl;
    ushort_t* Out = rel ? outn : outl;

    __shared__ float Wl[24][H];
    __shared__ float bf2s[2][H];
    __shared__ float G[16][2][8];
    __shared__ float S8r[16][8];

    int tid = threadIdx.x;
    for (int p = tid; p < 24 * H; p += 256) {
        int kk = p >> 7, c = p & 127;
        int srcrow = (kk >> 3) * 128 + (kk & 7);
        Wl[kk][c] = Ws[srcrow * H + c];
    }
    if (tid < 128) { bf2s[0][tid] = bmp[tid]; bf2s[1][tid] = bu[tid]; }

    int rl = tid >> 4;
    int t16 = tid & 15;
    int row = blockIdx.x * 16 + rl;
    {
        int c = t16 & 7, q = t16 >> 3;
        int beg = off[row], end = off[row + 1];
        float s = 0.f;
        for (int i = beg + q; i < end; i += 2)
            s += Xg[(size_t)adj[i] * FR + c];
        G[rl][q][c] = s;
    }
    __syncthreads();
    if (t16 < 8) S8r[rl][t16] = G[rl][0][t16] + G[rl][1][t16];
    __syncthreads();

    float d = deg[row];
    float a[16];
#pragma unroll
    for (int j = 0; j < 8; ++j) a[j] = S8r[rl][j];
    *(float4*)(a + 8)  = *(const float4*)(Xo + (size_t)row * FR);
    *(float4*)(a + 12) = *(const float4*)(Xo + (size_t)row * FR + 4);

    int c0 = t16 * 8;
    float acc[8] = {};
#pragma unroll
    for (int k = 0; k < 8; ++k) {
        float4 w0 = *(const float4*)(&Wl[k][c0]);
        float4 w1 = *(const float4*)(&Wl[k][c0 + 4]);
        float av = a[k];
        acc[0] += av * w0.x; acc[1] += av * w0.y; acc[2] += av * w0.z; acc[3] += av * w0.w;
        acc[4] += av * w1.x; acc[5] += av * w1.y; acc[6] += av * w1.z; acc[7] += av * w1.w;
    }
#pragma unroll
    for (int k = 0; k < 8; ++k) {
        float4 w0 = *(const float4*)(&Wl[8 + k][c0]);
        float4 w1 = *(const float4*)(&Wl[8 + k][c0 + 4]);
        float av = d * a[8 + k];
        acc[0] += av * w0.x; acc[1] += av * w0.y; acc[2] += av * w0.z; acc[3] += av * w0.w;
        acc[4] += av * w1.x; acc[5] += av * w1.y; acc[6] += av * w1.z; acc[7] += av * w1.w;
    }
#pragma unroll
    for (int k = 0; k < 8; ++k) {
        float4 w0 = *(const float4*)(&Wl[16 + k][c0]);
        float4 w1 = *(const float4*)(&Wl[16 + k][c0 + 4]);
        float av = a[8 + k];
        acc[0] += av * w0.x; acc[1] += av * w0.y; acc[2] += av * w0.z; acc[3] += av * w0.w;
        acc[4] += av * w1.x; acc[5] += av * w1.y; acc[6] += av * w1.z; acc[7] += av * w1.w;
    }

    float o[8];
#pragma unroll
    for (int j = 0; j < 8; ++j)
        o[j] = fmaxf(acc[j] + d * bf2s[0][c0 + j] + bf2s[1][c0 + j], 0.f);
    *(uint4*)(Out + (size_t)row * H + c0) = pk8(o);
}

// ---------------- layer-2: fused gather + MFMA GEMM + pooled epilogue ----------------
// LINK relation only (node update is dead code). No global row writes:
// relu(out) is reduced over rows in-register and atomicAdd'ed into sums.
__launch_bounds__(256)
__global__ void gemm_mfma_pool(const int* __restrict__ offL, const int* __restrict__ adjL,
                               const ushort_t* __restrict__ xlb, const ushort_t* __restrict__ xnb,
                               const float* __restrict__ dgl,
                               const ushort_t* __restrict__ WbLin, const float* __restrict__ bmpAll,
                               const float* __restrict__ bu_nl,
                               const int* __restrict__ batch, float* __restrict__ sums, int M) {
    const int* off = offL;
    const int* adj = adjL;
    const ushort_t* Xg = xnb;    // gather node state
    const ushort_t* Xo = xlb;    // own link rows
    const float* deg = dgl;
    const ushort_t* Wb = WbLin;
    const float* bmp = bmpAll + 2 * H;
    const float* bu  = bu_nl + H;

    __shared__ ushort_t T[TROWS * TSTR];   // 8.7 KB

    int tid = threadIdx.x;
    int lane = tid & 63;
    int wave = tid >> 6;
    int m0 = blockIdx.x * TROWS;
    int lrow = lane & 15, lg = lane >> 4;

    // staging: 8 threads/row, 16 bf16 cols (2x uint4) each
    int trow = tid >> 3, chunk = tid & 7;
    int grow = m0 + trow;
    bool vr = grow < M;
    int cbase = chunk * 16;

    // ---- phase A: gather S (fp32 accum, 2-neighbor unroll) -> bf16 tile ----
    {
        float a[16];
#pragma unroll
        for (int j = 0; j < 16; ++j) a[j] = 0.f;
        if (vr) {
            int beg = off[grow], end = off[grow + 1];
            int i = beg;
            for (; i + 1 < end; i += 2) {
                const uint4* p0 = (const uint4*)(Xg + (size_t)adj[i] * H + cbase);
                const uint4* p1 = (const uint4*)(Xg + (size_t)adj[i + 1] * H + cbase);
                uint4 u0 = p0[0], u1 = p0[1];
                uint4 v0 = p1[0], v1 = p1[1];
                addpk8(a, u0); addpk8(a + 8, u1);
                addpk8(a, v0); addpk8(a + 8, v1);
            }
            if (i < end) {
                const uint4* p0 = (const uint4*)(Xg + (size_t)adj[i] * H + cbase);
                addpk8(a, p0[0]); addpk8(a + 8, p0[1]);
            }
        }
        uint4* dst = (uint4*)&T[trow * TSTR + cbase];
        dst[0] = pk8(a); dst[1] = pk8(a + 8);
    }

    f32x4 acc[2][2];
#pragma unroll
    for (int i = 0; i < 2; ++i)
#pragma unroll
        for (int j = 0; j < 2; ++j)
            acc[i][j] = (f32x4){0.f, 0.f, 0.f, 0.f};

    __syncthreads();
    // ---- kts 0..3: piece S ----
#pragma unroll
    for (int kk = 0; kk < 4; ++kk) {
        bf16x8 af[2], bfv[2];
#pragma unroll
        for (int mf = 0; mf < 2; ++mf)
            af[mf] = *(const bf16x8*)&T[(mf * 16 + lrow) * TSTR + kk * 32 + lg * 8];
#pragma unroll
        for (int nf = 0; nf < 2; ++nf)
            bfv[nf] = *(const bf16x8*)(Wb + (size_t)kk * 4096
                        + (wave * 32 + nf * 16 + lrow) * 32 + lg * 8);
#pragma unroll
        for (int mf = 0; mf < 2; ++mf)
#pragma unroll
            for (int nf = 0; nf < 2; ++nf)
                acc[mf][nf] = __builtin_amdgcn_mfma_f32_16x16x32_bf16(
                    af[mf], bfv[nf], acc[mf][nf], 0, 0, 0);
    }
    __syncthreads();

    // ---- phase B: own x row (stash) -> deg-scaled tile ----
    uint4 xs0, xs1;
    {
        if (vr) {
            const uint4* p = (const uint4*)(Xo + (size_t)grow * H + cbase);
            xs0 = p[0]; xs1 = p[1];
        } else {
            xs0 = xs1 = make_uint4(0u, 0u, 0u, 0u);
        }
        float dr = vr ? deg[grow] : 0.f;
        uint4 w0 = xs0, w1 = xs1;
        unsigned* wp0 = (unsigned*)&w0;
        unsigned* wp1 = (unsigned*)&w1;
#pragma unroll
        for (int q = 0; q < 4; ++q) {
            float v0 = dr * bf2f((ushort_t)(wp0[q] & 0xFFFF));
            float v1 = dr * bf2f((ushort_t)(wp0[q] >> 16));
            wp0[q] = (unsigned)f2bf(v0) | ((unsigned)f2bf(v1) << 16);
            float v2 = dr * bf2f((ushort_t)(wp1[q] & 0xFFFF));
            float v3 = dr * bf2f((ushort_t)(wp1[q] >> 16));
            wp1[q] = (unsigned)f2bf(v2) | ((unsigned)f2bf(v3) << 16);
        }
        uint4* dst = (uint4*)&T[trow * TSTR + cbase];
        dst[0] = w0; dst[1] = w1;
    }
    __syncthreads();
    // ---- kts 4..7: piece deg*X ----
#pragma unroll
    for (int kk = 0; kk < 4; ++kk) {
        bf16x8 af[2], bfv[2];
#pragma unroll
        for (int mf = 0; mf < 2; ++mf)
            af[mf] = *(const bf16x8*)&T[(mf * 16 + lrow) * TSTR + kk * 32 + lg * 8];
#pragma unroll
        for (int nf = 0; nf < 2; ++nf)
            bfv[nf] = *(const bf16x8*)(Wb + (size_t)(4 + kk) * 4096
                        + (wave * 32 + nf * 16 + lrow) * 32 + lg * 8);
#pragma unroll
        for (int mf = 0; mf < 2; ++mf)
#pragma unroll
            for (int nf = 0; nf < 2; ++nf)
                acc[mf][nf] = __builtin_amdgcn_mfma_f32_16x16x32_bf16(
                    af[mf], bfv[nf], acc[mf][nf], 0, 0, 0);
    }
    __syncthreads();

    // ---- phase C: unscaled x tile (from stash) ----
    {
        uint4* dst = (uint4*)&T[trow * TSTR + cbase];
        dst[0] = xs0; dst[1] = xs1;
    }
    __syncthreads();
    // ---- kts 8..11: piece X ----
#pragma unroll
    for (int kk = 0; kk < 4; ++kk) {
        bf16x8 af[2], bfv[2];
#pragma unroll
        for (int mf = 0; mf < 2; ++mf)
            af[mf] = *(const bf16x8*)&T[(mf * 16 + lrow) * TSTR + kk * 32 + lg * 8];
#pragma unroll
        for (int nf = 0; nf < 2; ++nf)
            bfv[nf] = *(const bf16x8*)(Wb + (size_t)(8 + kk) * 4096
                        + (wave * 32 + nf * 16 + lrow) * 32 + lg * 8);
#pragma unroll
        for (int mf = 0; mf < 2; ++mf)
#pragma unroll
            for (int nf = 0; nf < 2; ++nf)
                acc[mf][nf] = __builtin_amdgcn_mfma_f32_16x16x32_bf16(
                    af[mf], bfv[nf], acc[mf][nf], 0, 0, 0);
    }

    // ---- epilogue: bias + relu + fused mean-pool (no global row writes) ----
    float bmpv[2], buv[2];
#pragma unroll
    for (int nf = 0; nf < 2; ++nf) {
        int col = wave * 32 + nf * 16 + lrow;
        bmpv[nf] = bmp[col];
        buv[nf] = bu[col];
    }
    int lastrow = min(m0 + TROWS, M) - 1;
    int g0 = batch[m0];
    int g1 = batch[lastrow];
    if (g0 == g1) {
        // fast path: whole tile in one batch group
        float ps0 = 0.f, ps1 = 0.f;
#pragma unroll
        for (int mf = 0; mf < 2; ++mf) {
#pragma unroll
            for (int r = 0; r < 4; ++r) {
                int row = m0 + mf * 16 + lg * 4 + r;
                if (row < M) {
                    float d = deg[row];
                    ps0 += fmaxf(acc[mf][0][r] + d * bmpv[0] + buv[0], 0.f);
                    ps1 += fmaxf(acc[mf][1][r] + d * bmpv[1] + buv[1], 0.f);
                }
            }
        }
        // reduce over the 4 lg lanes (lane ^ 16, lane ^ 32)
        ps0 += __shfl_xor(ps0, 16); ps0 += __shfl_xor(ps0, 32);
        ps1 += __shfl_xor(ps1, 16); ps1 += __shfl_xor(ps1, 32);
        if (lg == 0) {
            atomicAdd(&sums[g0 * H + wave * 32 + lrow], ps0);
            atomicAdd(&sums[g0 * H + wave * 32 + 16 + lrow], ps1);
        }
    } else {
        // slow path: per-row group
#pragma unroll
        for (int mf = 0; mf < 2; ++mf) {
#pragma unroll
            for (int r = 0; r < 4; ++r) {
                int row = m0 + mf * 16 + lg * 4 + r;
                if (row < M) {
                    float d = deg[row];
                    int g = batch[row];
                    float v0 = fmaxf(acc[mf][0][r] + d * bmpv[0] + buv[0], 0.f);
                    float v1 = fmaxf(acc[mf][1][r] + d * bmpv[1] + buv[1], 0.f);
                    atomicAdd(&sums[g * H + wave * 32 + lrow], v0);
                    atomicAdd(&sums[g * H + wave * 32 + 16 + lrow], v1);
                }
            }
        }
    }
}

// ---------------- pool finalize (counts via binary search) ----------------
__global__ void pool_final(const float* __restrict__ sums, const int* __restrict__ batch,
                           float* __restrict__ out) {
    int idx = blockIdx.x * blockDim.x + threadIdx.x;
    int g = idx / H;
    int lo = 0, hi = NL;
    while (lo < hi) { int mid = (lo + hi) >> 1; if (batch[mid] < g) lo = mid + 1; else hi = mid; }
    int first = lo;
    lo = 0; hi = NL;
    while (lo < hi) { int mid = (lo + hi) >> 1; if (batch[mid] < g + 1) lo = mid + 1; else hi = mid; }
    float cnt = (float)(lo - first);
    out[idx] = sums[idx] / fmaxf(cnt, 1.f);
}

static inline size_t rup(size_t n) { return (n + 15) & ~(size_t)15; }

extern "C" void kernel_launch(void* const* d_in, const int* in_sizes, int n_in,
                              void* d_out, int out_size, void* d_ws, size_t ws_size,
                              hipStream_t stream) {
    const float* x_node = (const float*)d_in[0];
    const float* x_link = (const float*)d_in[1];
    const float* Wm_nl  = (const float*)d_in[2];
    const float* bm_nl  = (const float*)d_in[3];
    const float* Wu_nl  = (const float*)d_in[4];
    const float* bu_nl  = (const float*)d_in[5];
    const float* Wm_ln  = (const float*)d_in[6];
    const float* bm_ln  = (const float*)d_in[7];
    const float* Wu_ln  = (const float*)d_in[8];
    const float* bu_ln  = (const float*)d_in[9];
    const int* nl_edge  = (const int*)d_in[10];
    const int* ln_edge  = (const int*)d_in[11];
    const int* batch_link = (const int*)d_in[12];
    (void)in_sizes; (void)n_in; (void)out_size; (void)ws_size;

    char* wsb = (char*)d_ws;
    size_t o = 0;
    auto alloc = [&](size_t elems) { void* p = wsb + o * 4; o += rup(elems); return p; };
    ushort_t* xnb  = (ushort_t*)alloc((size_t)NN * H / 2);   // bf16 state after layer 1
    ushort_t* xlb  = (ushort_t*)alloc((size_t)NL * H / 2);
    float* deg_l = (float*)alloc(NL);
    float* deg_n = (float*)alloc(NN);
    int*   idl   = (int*)alloc(NL);
    int*   idn   = (int*)alloc(NN);
    int*   offL  = (int*)alloc(NL + 1);
    int*   offN  = (int*)alloc(NN + 1);
    int*   adjL  = (int*)alloc(NE);
    int*   adjN  = (int*)alloc(NE);
    float* Wstack= (float*)alloc(4L * 384 * H);
    float* bmp   = (float*)alloc(4 * H);
    ushort_t* WbLin = (ushort_t*)alloc(12 * 4096 / 2);   // link-update only
    uint_t* bbuf  = (uint_t*)alloc((size_t)2 * NB * BCAP);
    int*   bbase = (int*)alloc(2 * NB);
    float* sums  = (float*)alloc(NG * H);    // NG*H = 8192 (16-aligned)
    int*   gcount= (int*)alloc(2 * NB);      // contiguous after sums -> one memset

    hipMemsetAsync(sums, 0, ((size_t)NG * H + rup(2 * NB)) * 4, stream);

    precompute_w<<<(4 * (384 * H + H) + 255) / 256, 256, 0, stream>>>(
        Wm_nl, bm_nl, Wu_nl, Wm_ln, bm_ln, Wu_ln, Wstack, bmp, WbLin);

    // ---- CSR build ----
    bucket_scatter<<<dim3((NE + 2047) / 2048, 2), 256, 0, stream>>>(
        nl_edge, ln_edge, bbuf, gcount);
    bucket_deg2<<<dim3(NB + 1, 2), 256, 0, stream>>>(bbuf, gcount, idl, idn, bbase);
    scan_fill<<<dim3(NB, 2), 256, 0, stream>>>(
        idl, idn, bbase, offL, offN, deg_l, deg_n, bbuf, gcount, adjL, adjN);

    // ---- layer 1 (fused gather + GEMM, both relations) ----
    gemm_l1_f<<<dim3(NL / 16, 2), 256, 0, stream>>>(
        offL, adjL, offN, adjN, x_node, x_link, deg_l, deg_n,
        Wstack, bmp, bu_nl, bu_ln, xlb, xnb);

    // ---- layer 2 (LINK relation only; node update is dead) + fused pool ----
    gemm_mfma_pool<<<(NL + TROWS - 1) / TROWS, 256, 0, stream>>>(
        offL, adjL, xlb, xnb, deg_l, WbLin, bmp, bu_nl,
        batch_link, sums, NL);

    pool_final<<<(NG * H) / 256, 256, 0, stream>>>(sums, batch_link, (float*)d_out);
}